// Round 1
// baseline (59791.663 us; speedup 1.0000x reference)
//
#include <hip/hip_runtime.h>
#include <hip/hip_bf16.h>
#include <math.h>

// ---------------- conv 3x3 stride2 pad1 + leaky ----------------
template<int CIN, int IH, int IW, int OH, int OW>
__global__ __launch_bounds__(256)
void conv3x3_s2_p1_leaky(const float* __restrict__ in, const float* __restrict__ w,
                         const float* __restrict__ bias, float* __restrict__ out,
                         int B, int OC) {
    int idx = blockIdx.x * blockDim.x + threadIdx.x;
    int total = B * OC * OH * OW;
    if (idx >= total) return;
    int ox = idx % OW; int t = idx / OW;
    int oy = t % OH;   t /= OH;
    int oc = t % OC;   int b = t / OC;
    int iy0 = oy * 2 - 1, ix0 = ox * 2 - 1;
    float acc = bias[oc];
    const float* inb = in + (size_t)b * CIN * IH * IW;
    const float* wb  = w  + (size_t)oc * CIN * 9;
    for (int ic = 0; ic < CIN; ic++) {
        const float* ip = inb + (size_t)ic * IH * IW;
        const float* wp = wb + ic * 9;
        #pragma unroll
        for (int ky = 0; ky < 3; ky++) {
            int iy = iy0 + ky;
            if (iy < 0 || iy >= IH) continue;
            #pragma unroll
            for (int kx = 0; kx < 3; kx++) {
                int ix = ix0 + kx;
                if (ix < 0 || ix >= IW) continue;
                acc = fmaf(ip[iy * IW + ix], wp[ky * 3 + kx], acc);
            }
        }
    }
    out[idx] = acc >= 0.f ? acc : 0.01f * acc;
}

// ---------------- per-channel batchnorm (mean/var over B,H,W), in place ----------------
__global__ __launch_bounds__(256)
void bn_inplace(float* __restrict__ data, int C, int B, int HW) {
    int c = blockIdx.x;
    int count = B * HW;
    __shared__ double ssum[256];
    __shared__ double ssq[256];
    double s = 0.0, q = 0.0;
    for (int i = threadIdx.x; i < count; i += 256) {
        int b = i / HW, p = i % HW;
        float v = data[((size_t)(b * C + c)) * HW + p];
        s += v; q += (double)v * (double)v;
    }
    ssum[threadIdx.x] = s; ssq[threadIdx.x] = q;
    __syncthreads();
    for (int off = 128; off > 0; off >>= 1) {
        if ((int)threadIdx.x < off) {
            ssum[threadIdx.x] += ssum[threadIdx.x + off];
            ssq[threadIdx.x]  += ssq[threadIdx.x + off];
        }
        __syncthreads();
    }
    __shared__ float smean, sinv;
    if (threadIdx.x == 0) {
        double mean = ssum[0] / count;
        double var  = ssq[0] / count - mean * mean;
        smean = (float)mean;
        sinv  = (float)(1.0 / sqrt(var + 1e-5));
    }
    __syncthreads();
    float mean = smean, inv = sinv;
    for (int i = threadIdx.x; i < count; i += 256) {
        int b = i / HW, p = i % HW;
        size_t o = ((size_t)(b * C + c)) * HW + p;
        data[o] = (data[o] - mean) * inv;
    }
}

// ---------------- fc + relu: (100,16384)@(16384,800) ----------------
__global__ __launch_bounds__(256)
void fc_relu(const float* __restrict__ h, const float* __restrict__ w,
             const float* __restrict__ bias, float* __restrict__ out) {
    int idx = blockIdx.x * blockDim.x + threadIdx.x;
    if (idx >= 100 * 800) return;
    int n = idx % 800, b = idx / 800;
    const float* hp = h + (size_t)b * 16384;
    float acc = bias[n];
    for (int k = 0; k < 16384; k++)
        acc = fmaf(hp[k], w[(size_t)k * 800 + n], acc);
    out[idx] = fmaxf(acc, 0.f);
}

// ---------------- real 2D DFT: Yr[b,k1,k2] = sum sig*cos(2pi(8 k1 n1 + 100 k2 n2)/800) ----------------
__global__ __launch_bounds__(256)
void dft_real(const float* __restrict__ eig, float* __restrict__ Yr) {
    __shared__ float se[800];
    __shared__ float ctab[800];
    int b = blockIdx.x;
    for (int i = threadIdx.x; i < 800; i += 256) {
        se[i] = eig[b * 800 + i];
        ctab[i] = (float)cos(6.283185307179586 * (double)i / 800.0);
    }
    __syncthreads();
    for (int oi = threadIdx.x; oi < 800; oi += 256) {
        int k1 = oi >> 3, k2 = oi & 7;
        int d1 = k1 * 8;    // < 800
        int d2 = k2 * 100;  // < 800
        float acc = 0.f;
        int p1 = 0;
        for (int n1 = 0; n1 < 100; n1++) {
            int p = p1;
            #pragma unroll
            for (int n2 = 0; n2 < 8; n2++) {
                acc = fmaf(se[n1 * 8 + n2], ctab[p], acc);
                p += d2; if (p >= 800) p -= 800;
            }
            p1 += d1; if (p1 >= 800) p1 -= 800;
        }
        Yr[b * 800 + oi] = acc;
    }
}

// ---------------- C[b,i,j] = Yr[b,(i-j) mod 800] / sqrt(800) ----------------
__global__ __launch_bounds__(256)
void build_C(const float* __restrict__ Yr, float* __restrict__ C) {
    int idx = blockIdx.x * blockDim.x + threadIdx.x;
    if (idx >= 100 * 800 * 800) return;
    int j = idx % 800; int t = idx / 800;
    int i = t % 800;   int b = t / 800;
    int k = i - j; if (k < 0) k += 800;
    C[idx] = Yr[b * 800 + k] * 0.035355339059327376f;
}

// ---------------- dec: (100,800)@(800,9216) + bias ----------------
__global__ __launch_bounds__(256)
void dec_mm(const float* __restrict__ Yr, const float* __restrict__ w,
            const float* __restrict__ bias, float* __restrict__ out) {
    int idx = blockIdx.x * blockDim.x + threadIdx.x;
    if (idx >= 100 * 9216) return;
    int m = idx % 9216, b = idx / 9216;
    float acc = bias[m];
    const float* yp = Yr + b * 800;
    for (int n = 0; n < 800; n++)
        acc = fmaf(yp[n], w[(size_t)n * 9216 + m], acc);
    out[idx] = acc;
}

// ---------------- transposed conv 3x3 (gather form) ----------------
// w layout: [CIN, OC, 3, 3]; out[oy] += in[iy]*w[ky] where iy=(oy+P-ky)/S when divisible
__global__ __launch_bounds__(256)
void convT3x3(const float* __restrict__ in, const float* __restrict__ w,
              const float* __restrict__ bias, float* __restrict__ out,
              int B, int CIN, int IH, int IW, int OC, int OH, int OW, int S, int P) {
    int idx = blockIdx.x * blockDim.x + threadIdx.x;
    int total = B * OC * OH * OW;
    if (idx >= total) return;
    int ox = idx % OW; int t = idx / OW;
    int oy = t % OH;   t /= OH;
    int oc = t % OC;   int b = t / OC;
    float acc = bias[oc];
    for (int ky = 0; ky < 3; ky++) {
        int ty = oy + P - ky;
        if (ty < 0 || (ty % S)) continue;
        int iy = ty / S; if (iy >= IH) continue;
        for (int kx = 0; kx < 3; kx++) {
            int tx = ox + P - kx;
            if (tx < 0 || (tx % S)) continue;
            int ix = tx / S; if (ix >= IW) continue;
            const float* ip = in + ((size_t)(b * CIN) * IH + iy) * IW + ix;
            const float* wp = w + (size_t)oc * 9 + ky * 3 + kx;
            float s = 0.f;
            for (int ic = 0; ic < CIN; ic++)
                s = fmaf(ip[(size_t)ic * IH * IW], wp[(size_t)ic * OC * 9], s);
            acc += s;
        }
    }
    out[idx] = acc;
}

extern "C" void kernel_launch(void* const* d_in, const int* in_sizes, int n_in,
                              void* d_out, int out_size, void* d_ws, size_t ws_size,
                              hipStream_t stream) {
    const float* x    = (const float*)d_in[0];
    const float* c1w  = (const float*)d_in[1];  const float* c1b = (const float*)d_in[2];
    const float* c2w  = (const float*)d_in[3];  const float* c2b = (const float*)d_in[4];
    const float* c3w  = (const float*)d_in[5];  const float* c3b = (const float*)d_in[6];
    const float* c4w  = (const float*)d_in[7];  const float* c4b = (const float*)d_in[8];
    const float* fcw  = (const float*)d_in[9];  const float* fcb = (const float*)d_in[10];
    const float* decw = (const float*)d_in[11]; const float* decb = (const float*)d_in[12];
    const float* t1w  = (const float*)d_in[13]; const float* t1b = (const float*)d_in[14];
    const float* t2w  = (const float*)d_in[15]; const float* t2b = (const float*)d_in[16];
    const float* t3w  = (const float*)d_in[17]; const float* t3b = (const float*)d_in[18];
    const float* t4w  = (const float*)d_in[19]; const float* t4b = (const float*)d_in[20];
    const float* t5w  = (const float*)d_in[21]; const float* t5b = (const float*)d_in[22];

    float* out = (float*)d_out;
    float* ws  = (float*)d_ws;

    // Output layout: d (240100) | C (64,000,000) | eig (80,000)
    float* d_final = out;
    float* Cmat    = out + 240100;
    float* eig     = out + 240100 + 64000000;

    // Workspace ping-pong regions (total ~109 MB of floats)
    float* A  = ws;              // 13,107,200 floats (52.4 MB)
    float* Bp = ws + 13107200;   // 14,137,600 floats (56.5 MB)

    float* h1 = A;    // (100,128,32,32)
    float* h2 = Bp;   // (100,256,16,16)
    float* h3 = A;    // (100,1024,8,8)
    float* h4 = Bp;   // (100,1024,4,4)
    float* Yr = A;    // (100,800)
    float* d0 = Bp;   // (100,9216)
    float* o1 = A;    // (100,512,5,5)    = 1,280,000
    float* o2 = Bp;   // (100,256,11,11)  = 3,097,600
    float* o3 = A;    // (100,128,23,23)  = 6,771,200
    float* o4 = Bp;   // (100,64,47,47)   = 14,137,600

    const int TB = 256;
    #define GRID(n) dim3(((n) + TB - 1) / TB)

    conv3x3_s2_p1_leaky<1, 64, 64, 32, 32><<<GRID(13107200), TB, 0, stream>>>(x,  c1w, c1b, h1, 100, 128);
    bn_inplace<<<dim3(128),  TB, 0, stream>>>(h1, 128, 100, 1024);
    conv3x3_s2_p1_leaky<128, 32, 32, 16, 16><<<GRID(6553600), TB, 0, stream>>>(h1, c2w, c2b, h2, 100, 256);
    bn_inplace<<<dim3(256),  TB, 0, stream>>>(h2, 256, 100, 256);
    conv3x3_s2_p1_leaky<256, 16, 16, 8, 8><<<GRID(6553600), TB, 0, stream>>>(h2, c3w, c3b, h3, 100, 1024);
    bn_inplace<<<dim3(1024), TB, 0, stream>>>(h3, 1024, 100, 64);
    conv3x3_s2_p1_leaky<1024, 8, 8, 4, 4><<<GRID(1638400), TB, 0, stream>>>(h3, c4w, c4b, h4, 100, 1024);
    bn_inplace<<<dim3(1024), TB, 0, stream>>>(h4, 1024, 100, 16);

    fc_relu<<<GRID(80000), TB, 0, stream>>>(h4, fcw, fcb, eig);
    dft_real<<<dim3(100), TB, 0, stream>>>(eig, Yr);
    build_C<<<GRID(64000000), TB, 0, stream>>>(Yr, Cmat);
    dec_mm<<<GRID(921600), TB, 0, stream>>>(Yr, decw, decb, d0);

    convT3x3<<<GRID(1280000),  TB, 0, stream>>>(d0, t1w, t1b, o1, 100, 1024, 3, 3, 512, 5, 5, 2, 1);
    convT3x3<<<GRID(3097600),  TB, 0, stream>>>(o1, t2w, t2b, o2, 100, 512, 5, 5, 256, 11, 11, 2, 0);
    convT3x3<<<GRID(6771200),  TB, 0, stream>>>(o2, t3w, t3b, o3, 100, 256, 11, 11, 128, 23, 23, 2, 0);
    convT3x3<<<GRID(14137600), TB, 0, stream>>>(o3, t4w, t4b, o4, 100, 128, 23, 23, 64, 47, 47, 2, 0);
    convT3x3<<<GRID(240100),   TB, 0, stream>>>(o4, t5w, t5b, d_final, 100, 64, 47, 47, 1, 49, 49, 1, 0);

    #undef GRID
}

// Round 2
// 8926.501 us; speedup vs baseline: 6.6982x; 6.6982x over previous
//
#include <hip/hip_runtime.h>
#include <math.h>

#define TPB 256

// ---------------- naive conv 3x3 stride2 pad1 + leaky (used for conv1, CIN=1) ----------------
template<int CIN, int IH, int IW, int OH, int OW>
__global__ __launch_bounds__(256)
void conv3x3_s2_p1_leaky(const float* __restrict__ in, const float* __restrict__ w,
                         const float* __restrict__ bias, float* __restrict__ out,
                         int B, int OC) {
    int idx = blockIdx.x * blockDim.x + threadIdx.x;
    int total = B * OC * OH * OW;
    if (idx >= total) return;
    int ox = idx % OW; int t = idx / OW;
    int oy = t % OH;   t /= OH;
    int oc = t % OC;   int b = t / OC;
    int iy0 = oy * 2 - 1, ix0 = ox * 2 - 1;
    float acc = bias[oc];
    const float* inb = in + (size_t)b * CIN * IH * IW;
    const float* wb  = w  + (size_t)oc * CIN * 9;
    for (int ic = 0; ic < CIN; ic++) {
        const float* ip = inb + (size_t)ic * IH * IW;
        const float* wp = wb + ic * 9;
        #pragma unroll
        for (int ky = 0; ky < 3; ky++) {
            int iy = iy0 + ky;
            if (iy < 0 || iy >= IH) continue;
            #pragma unroll
            for (int kx = 0; kx < 3; kx++) {
                int ix = ix0 + kx;
                if (ix < 0 || ix >= IW) continue;
                acc = fmaf(ip[iy * IW + ix], wp[ky * 3 + kx], acc);
            }
        }
    }
    out[idx] = acc >= 0.f ? acc : 0.01f * acc;
}

// ---------------- per-channel batchnorm, in place ----------------
__global__ __launch_bounds__(256)
void bn_inplace(float* __restrict__ data, int C, int B, int HW) {
    int c = blockIdx.x;
    int count = B * HW;
    __shared__ double ssum[256];
    __shared__ double ssq[256];
    double s = 0.0, q = 0.0;
    for (int i = threadIdx.x; i < count; i += 256) {
        int b = i / HW, p = i % HW;
        float v = data[((size_t)(b * C + c)) * HW + p];
        s += v; q += (double)v * (double)v;
    }
    ssum[threadIdx.x] = s; ssq[threadIdx.x] = q;
    __syncthreads();
    for (int off = 128; off > 0; off >>= 1) {
        if ((int)threadIdx.x < off) {
            ssum[threadIdx.x] += ssum[threadIdx.x + off];
            ssq[threadIdx.x]  += ssq[threadIdx.x + off];
        }
        __syncthreads();
    }
    __shared__ float smean, sinv;
    if (threadIdx.x == 0) {
        double mean = ssum[0] / count;
        double var  = ssq[0] / count - mean * mean;
        smean = (float)mean;
        sinv  = (float)(1.0 / sqrt(var + 1e-5));
    }
    __syncthreads();
    float mean = smean, inv = sinv;
    for (int i = threadIdx.x; i < count; i += 256) {
        int b = i / HW, p = i % HW;
        size_t o = ((size_t)(b * C + c)) * HW + p;
        data[o] = (data[o] - mean) * inv;
    }
}

// ============ tiled implicit-GEMM ============
// MODE 0: gemm  A[M,K] row-major, B[K,N] row-major
// MODE 1: conv3x3 s2 p1: A=im2col(in NCHW), B=w [OC][CIN*9]  (oc-major)
// MODE 2: convT3x3 s2 pad P: A=gather (zeros on invalid taps), B=w [CIN][OC][9]
// thread micro-tile rows: (i/4)*(BM/2) + tm*4 + i%4  (keeps LDS aliasing <=2-way)
template<int MODE,int BM,int BN,int BK,int TM,int TN,bool LEAKY,bool SPLIT>
__global__ __launch_bounds__(TPB)
void tile_mm(const float* __restrict__ Ain, const float* __restrict__ Bw,
             const float* __restrict__ bias, float* __restrict__ out,
             int M, int N, int K,
             int CIN, int IH, int IW, int OH, int OW, int P) {
    __shared__ float As[BK][BM + 4];
    __shared__ float Bs[BK][BN + 4];
    const int t  = threadIdx.x;
    const int mt = blockIdx.x, nt = blockIdx.y;
    int k0 = 0, kend = K;
    if (SPLIT) { int chunk = K / gridDim.z; k0 = blockIdx.z * chunk; kend = k0 + chunk; }

    const int tm = t & 15, tn = t >> 4;

    // --- staging precompute ---
    int s_ml = 0, s_oy = 0, s_ox = 0; bool s_mv = false;
    const float* inb = Ain;
    if (MODE != 0) {
        s_ml = t % BM;
        int gm = mt * BM + s_ml;
        s_mv = gm < M;
        int b = 0;
        if (s_mv) {
            int ohw = OH * OW;
            b = gm / ohw; int r = gm - b * ohw;
            s_oy = r / OW; s_ox = r - s_oy * OW;
        }
        inb = Ain + (size_t)b * CIN * IH * IW;
    }
    int s_n = t % BN;           // MODE0 B staging column
    int gnB = nt * BN + s_n;

    float acc[TM][TN];
    #pragma unroll
    for (int i = 0; i < TM; i++)
        #pragma unroll
        for (int j = 0; j < TN; j++) acc[i][j] = 0.f;
    if (!SPLIT && bias != nullptr) {
        #pragma unroll
        for (int j = 0; j < TN; j++) {
            int gn = nt * BN + (j >> 2) * (BN / 2) + tn * 4 + (j & 3);
            float bv = (gn < N) ? bias[gn] : 0.f;
            #pragma unroll
            for (int i = 0; i < TM; i++) acc[i][j] = bv;
        }
    }

    for (int kb = k0; kb < kend; kb += BK) {
        // ---- stage A ----
        if (MODE == 0) {
            const int kk = t % BK;
            #pragma unroll
            for (int i = 0; i < BM * BK / TPB; i++) {
                int ml = t / BK + i * (TPB / BK);
                int gm = mt * BM + ml;
                float v = 0.f;
                if (gm < M) v = Ain[(size_t)gm * K + kb + kk];
                As[kk][ml] = v;
            }
        } else {
            #pragma unroll
            for (int i = 0; i < BM * BK / TPB; i++) {
                int kk = t / BM + i * (TPB / BM);
                int k = kb + kk;
                int ic = k / 9; int tap = k - ic * 9;
                int ky = tap / 3; int kx = tap - ky * 3;
                float v = 0.f;
                if (MODE == 1) {
                    int iy = s_oy * 2 - 1 + ky, ix = s_ox * 2 - 1 + kx;
                    if (s_mv && (unsigned)iy < (unsigned)IH && (unsigned)ix < (unsigned)IW)
                        v = inb[((size_t)ic * IH + iy) * IW + ix];
                } else {
                    int ty = s_oy + P - ky, tx = s_ox + P - kx;
                    if (s_mv && ty >= 0 && tx >= 0 && !(ty & 1) && !(tx & 1)) {
                        int iy = ty >> 1, ix = tx >> 1;
                        if (iy < IH && ix < IW) v = inb[((size_t)ic * IH + iy) * IW + ix];
                    }
                }
                As[kk][s_ml] = v;
            }
        }
        // ---- stage B ----
        if (MODE == 0) {
            #pragma unroll
            for (int i = 0; i < BN * BK / TPB; i++) {
                int kk = t / BN + i * (TPB / BN);
                float v = 0.f;
                if (gnB < N) v = Bw[(size_t)(kb + kk) * N + gnB];
                Bs[kk][s_n] = v;
            }
        } else {
            const int kk = t % BK;
            int k = kb + kk;
            int ic = k / 9; int tap = k - ic * 9;
            #pragma unroll
            for (int i = 0; i < BN * BK / TPB; i++) {
                int nl = t / BK + i * (TPB / BK);
                int gn = nt * BN + nl;
                float v = 0.f;
                if (gn < N) {
                    if (MODE == 1) v = Bw[(size_t)gn * K + k];
                    else           v = Bw[((size_t)ic * N + gn) * 9 + tap];
                }
                Bs[kk][nl] = v;
            }
        }
        __syncthreads();
        // ---- compute ----
        #pragma unroll
        for (int kk = 0; kk < BK; kk++) {
            float a[TM], bb[TN];
            #pragma unroll
            for (int g = 0; g < TM / 4; g++)
                *(float4*)&a[g * 4] = *(const float4*)&As[kk][g * (BM / 2) + tm * 4];
            #pragma unroll
            for (int g = 0; g < TN / 4; g++)
                *(float4*)&bb[g * 4] = *(const float4*)&Bs[kk][g * (BN / 2) + tn * 4];
            #pragma unroll
            for (int i = 0; i < TM; i++)
                #pragma unroll
                for (int j = 0; j < TN; j++)
                    acc[i][j] = fmaf(a[i], bb[j], acc[i][j]);
        }
        __syncthreads();
    }

    // ---- epilogue ----
    if (MODE == 0) {
        #pragma unroll
        for (int i = 0; i < TM; i++) {
            int gm = mt * BM + (i >> 2) * (BM / 2) + tm * 4 + (i & 3);
            if (gm >= M) continue;
            #pragma unroll
            for (int j = 0; j < TN; j++) {
                int gn = nt * BN + (j >> 2) * (BN / 2) + tn * 4 + (j & 3);
                if (gn >= N) continue;
                if (SPLIT) atomicAdd(&out[(size_t)gm * N + gn], acc[i][j]);
                else       out[(size_t)gm * N + gn] = acc[i][j];
            }
        }
    } else {
        int ohw = OH * OW;
        #pragma unroll
        for (int i = 0; i < TM; i++) {
            int gm = mt * BM + (i >> 2) * (BM / 2) + tm * 4 + (i & 3);
            if (gm >= M) continue;
            int b = gm / ohw; int r = gm - b * ohw;
            size_t base = (size_t)b * N * ohw + r;
            #pragma unroll
            for (int j = 0; j < TN; j++) {
                int gn = nt * BN + (j >> 2) * (BN / 2) + tn * 4 + (j & 3);
                if (gn >= N) continue;
                float v = acc[i][j];
                if (LEAKY) v = v >= 0.f ? v : 0.01f * v;
                out[base + (size_t)gn * ohw] = v;
            }
        }
    }
}

// ---------------- fc finalize: relu(acc + bias) ----------------
__global__ __launch_bounds__(256)
void finalize_relu(const float* __restrict__ acc, const float* __restrict__ bias,
                   float* __restrict__ out) {
    int i = blockIdx.x * blockDim.x + threadIdx.x;
    if (i >= 100 * 800) return;
    float v = acc[i] + bias[i % 800];
    out[i] = fmaxf(v, 0.f);
}

// ---------------- real 2D DFT ----------------
__global__ __launch_bounds__(256)
void dft_real(const float* __restrict__ eig, float* __restrict__ Yr) {
    __shared__ float se[800];
    __shared__ float ctab[800];
    int b = blockIdx.x;
    for (int i = threadIdx.x; i < 800; i += 256) {
        se[i] = eig[b * 800 + i];
        ctab[i] = (float)cos(6.283185307179586 * (double)i / 800.0);
    }
    __syncthreads();
    for (int oi = threadIdx.x; oi < 800; oi += 256) {
        int k1 = oi >> 3, k2 = oi & 7;
        int d1 = k1 * 8;
        int d2 = k2 * 100;
        float acc = 0.f;
        int p1 = 0;
        for (int n1 = 0; n1 < 100; n1++) {
            int p = p1;
            #pragma unroll
            for (int n2 = 0; n2 < 8; n2++) {
                acc = fmaf(se[n1 * 8 + n2], ctab[p], acc);
                p += d2; if (p >= 800) p -= 800;
            }
            p1 += d1; if (p1 >= 800) p1 -= 800;
        }
        Yr[b * 800 + oi] = acc;
    }
}

// ---------------- C[b,i,j] = Yr[b,(i-j) mod 800] / sqrt(800) ----------------
__global__ __launch_bounds__(256)
void build_C(const float* __restrict__ Yr, float* __restrict__ C) {
    int idx = blockIdx.x * blockDim.x + threadIdx.x;
    if (idx >= 100 * 800 * 800) return;
    int j = idx % 800; int t = idx / 800;
    int i = t % 800;   int b = t / 800;
    int k = i - j; if (k < 0) k += 800;
    C[idx] = Yr[b * 800 + k] * 0.035355339059327376f;
}

// ---------------- naive convT (ct5 only, OC=1) ----------------
__global__ __launch_bounds__(256)
void convT3x3(const float* __restrict__ in, const float* __restrict__ w,
              const float* __restrict__ bias, float* __restrict__ out,
              int B, int CIN, int IH, int IW, int OC, int OH, int OW, int S, int P) {
    int idx = blockIdx.x * blockDim.x + threadIdx.x;
    int total = B * OC * OH * OW;
    if (idx >= total) return;
    int ox = idx % OW; int t = idx / OW;
    int oy = t % OH;   t /= OH;
    int oc = t % OC;   int b = t / OC;
    float acc = bias[oc];
    for (int ky = 0; ky < 3; ky++) {
        int ty = oy + P - ky;
        if (ty < 0 || (ty % S)) continue;
        int iy = ty / S; if (iy >= IH) continue;
        for (int kx = 0; kx < 3; kx++) {
            int tx = ox + P - kx;
            if (tx < 0 || (tx % S)) continue;
            int ix = tx / S; if (ix >= IW) continue;
            const float* ip = in + ((size_t)(b * CIN) * IH + iy) * IW + ix;
            const float* wp = w + (size_t)oc * 9 + ky * 3 + kx;
            float s = 0.f;
            for (int ic = 0; ic < CIN; ic++)
                s = fmaf(ip[(size_t)ic * IH * IW], wp[(size_t)ic * OC * 9], s);
            acc += s;
        }
    }
    out[idx] = acc;
}

extern "C" void kernel_launch(void* const* d_in, const int* in_sizes, int n_in,
                              void* d_out, int out_size, void* d_ws, size_t ws_size,
                              hipStream_t stream) {
    const float* x    = (const float*)d_in[0];
    const float* c1w  = (const float*)d_in[1];  const float* c1b = (const float*)d_in[2];
    const float* c2w  = (const float*)d_in[3];  const float* c2b = (const float*)d_in[4];
    const float* c3w  = (const float*)d_in[5];  const float* c3b = (const float*)d_in[6];
    const float* c4w  = (const float*)d_in[7];  const float* c4b = (const float*)d_in[8];
    const float* fcw  = (const float*)d_in[9];  const float* fcb = (const float*)d_in[10];
    const float* decw = (const float*)d_in[11]; const float* decb = (const float*)d_in[12];
    const float* t1w  = (const float*)d_in[13]; const float* t1b = (const float*)d_in[14];
    const float* t2w  = (const float*)d_in[15]; const float* t2b = (const float*)d_in[16];
    const float* t3w  = (const float*)d_in[17]; const float* t3b = (const float*)d_in[18];
    const float* t4w  = (const float*)d_in[19]; const float* t4b = (const float*)d_in[20];
    const float* t5w  = (const float*)d_in[21]; const float* t5b = (const float*)d_in[22];

    float* out = (float*)d_out;
    float* ws  = (float*)d_ws;

    float* d_final = out;
    float* Cmat    = out + 240100;
    float* eig     = out + 240100 + 64000000;

    float* A  = ws;              // 13,107,200 floats
    float* Bp = ws + 13107200;   // 14,137,600 floats

    float* h1 = A;    float* h2 = Bp;  float* h3 = A;   float* h4 = Bp;
    float* facc = A;  float* Yr = A;   float* d0 = Bp;
    float* o1 = A;    float* o2 = Bp;  float* o3 = A;   float* o4 = Bp;

    const int TB = 256;
    #define GRID(n) dim3(((n) + TB - 1) / TB)
    #define MT(M, BM) (((M) + (BM) - 1) / (BM))

    // encoder
    conv3x3_s2_p1_leaky<1, 64, 64, 32, 32><<<GRID(13107200), TB, 0, stream>>>(x, c1w, c1b, h1, 100, 128);
    bn_inplace<<<dim3(128), TB, 0, stream>>>(h1, 128, 100, 1024);

    tile_mm<1,128,128,8,8,8,true,false><<<dim3(MT(25600,128), 2), TB, 0, stream>>>(
        h1, c2w, c2b, h2, 25600, 256, 1152, 128, 32, 32, 16, 16, 0);
    bn_inplace<<<dim3(256), TB, 0, stream>>>(h2, 256, 100, 256);

    tile_mm<1,128,128,8,8,8,true,false><<<dim3(MT(6400,128), 8), TB, 0, stream>>>(
        h2, c3w, c3b, h3, 6400, 1024, 2304, 256, 16, 16, 8, 8, 0);
    bn_inplace<<<dim3(1024), TB, 0, stream>>>(h3, 1024, 100, 64);

    tile_mm<1,64,128,8,4,8,true,false><<<dim3(MT(1600,64), 8), TB, 0, stream>>>(
        h3, c4w, c4b, h4, 1600, 1024, 9216, 1024, 8, 8, 4, 4, 0);
    bn_inplace<<<dim3(1024), TB, 0, stream>>>(h4, 1024, 100, 16);

    // fc (K-split + atomic accumulate), then relu finalize
    hipMemsetAsync(facc, 0, 80000 * sizeof(float), stream);
    tile_mm<0,64,64,16,4,4,false,true><<<dim3(MT(100,64), MT(800,64), 16), TB, 0, stream>>>(
        h4, fcw, nullptr, facc, 100, 800, 16384, 0, 0, 0, 0, 0, 0);
    finalize_relu<<<GRID(80000), TB, 0, stream>>>(facc, fcb, eig);

    dft_real<<<dim3(100), TB, 0, stream>>>(eig, Yr);
    build_C<<<GRID(64000000), TB, 0, stream>>>(Yr, Cmat);

    tile_mm<0,64,64,16,4,4,false,false><<<dim3(MT(100,64), MT(9216,64)), TB, 0, stream>>>(
        Yr, decw, decb, d0, 100, 9216, 800, 0, 0, 0, 0, 0, 0);

    // decoder convT stack
    tile_mm<2,64,64,16,4,4,false,false><<<dim3(MT(2500,64), MT(512,64)), TB, 0, stream>>>(
        d0, t1w, t1b, o1, 2500, 512, 9216, 1024, 3, 3, 5, 5, 1);
    tile_mm<2,128,64,8,8,4,false,false><<<dim3(MT(12100,128), MT(256,64)), TB, 0, stream>>>(
        o1, t2w, t2b, o2, 12100, 256, 4608, 512, 5, 5, 11, 11, 0);
    tile_mm<2,128,128,8,8,8,false,false><<<dim3(MT(52900,128), MT(128,128)), TB, 0, stream>>>(
        o2, t3w, t3b, o3, 52900, 128, 2304, 256, 11, 11, 23, 23, 0);
    tile_mm<2,128,64,8,8,4,false,false><<<dim3(MT(220900,128), MT(64,64)), TB, 0, stream>>>(
        o3, t4w, t4b, o4, 220900, 64, 1152, 128, 23, 23, 47, 47, 0);
    convT3x3<<<GRID(240100), TB, 0, stream>>>(o4, t5w, t5b, d_final, 100, 64, 47, 47, 1, 49, 49, 1, 0);

    #undef GRID
    #undef MT
}

// Round 3
// 3928.135 us; speedup vs baseline: 15.2214x; 2.2725x over previous
//
#include <hip/hip_runtime.h>
#include <math.h>

typedef __attribute__((ext_vector_type(8))) short bf16x8;
typedef __attribute__((ext_vector_type(4))) float f32x4;

__device__ __forceinline__ unsigned short f2bf(float f) {
    unsigned u = __builtin_bit_cast(unsigned, f);
    u += 0x7FFFu + ((u >> 16) & 1u);   // RNE
    return (unsigned short)(u >> 16);
}

// ================= MFMA implicit-GEMM =================
// MODE 0: A[M,K] fp32 row-major, Bw = bf16 [N][K] (pre-transposed)
// MODE 1: conv3x3 s2 p1, A = im2col(in NCHW fp32), Bw = bf16 [OC][CIN*9]
// MODE 2: convT3x3 s2 pad P, A = gather(zeros invalid), Bw = bf16 [OC][CIN*9] (pre-permuted)
// 256 thr = 4 waves (2x2); wave tile (BM/2)x(BN/2); mfma 16x16x32 bf16.
// LDS layout [k/8][row][8] halfwords: 16B-aligned b128 frags, ~2-way bank aliasing (free).
template<int MODE, int BM, int BN, bool LEAKY, bool SPLIT>
__global__ __launch_bounds__(256, 2)
void mfma_mm(const float* __restrict__ Af, const unsigned short* __restrict__ Bw,
             const float* __restrict__ bias, float* __restrict__ out,
             int M, int N, int K,
             int CIN, int IH, int IW, int OH, int OW, int P, int zchunk)
{
    constexpr int RM = BM / 32, RN = BN / 32;
    __shared__ unsigned short As[4 * BM * 8];
    __shared__ unsigned short Bs[4 * BN * 8];
    const int t = threadIdx.x;
    const int lane = t & 63;
    const int wave = t >> 6;
    const int lm = lane & 15, quad = lane >> 4;
    const int wm = wave & 1, wn = wave >> 1;
    const int mt = blockIdx.x, nt = blockIdx.y;
    int k0 = 0, kend = K;
    if (SPLIT) { k0 = blockIdx.z * zchunk; kend = k0 + zchunk; }

    // A staging: thread -> (row am, k-half)
    const int am  = t >> 1;
    const int akh = (t & 1) * 2;
    const bool a_act = am < BM;
    const int a_gm = mt * BM + am;
    int oy = 0, ox = 0; bool mv = false;
    const float* inb = Af;
    if (MODE != 0) {
        mv = a_act && (a_gm < M);
        int ohw = OH * OW;
        int bb = mv ? a_gm / ohw : 0;
        int rr = a_gm - bb * ohw;
        oy = rr / OW; ox = rr - oy * OW;
        inb = Af + (size_t)bb * CIN * IH * IW;
    }
    // B staging
    const int bn_ = t >> 1;
    const int bkh = (t & 1) * 2;
    const bool b_act = bn_ < BN;
    const int b_gn = nt * BN + bn_;
    const bool b_inr = b_act && (b_gn < N);

    f32x4 acc[RM][RN];
    #pragma unroll
    for (int i = 0; i < RM; i++)
        #pragma unroll
        for (int j = 0; j < RN; j++) acc[i][j] = (f32x4){0.f, 0.f, 0.f, 0.f};

    for (int kb = k0; kb < kend; kb += 32) {
        // ---- stage A (fp32 -> bf16) ----
        if (a_act) {
            unsigned short av[16];
            if (MODE == 0) {
                if (a_gm < M) {
                    const f32x4* p = (const f32x4*)(Af + (size_t)a_gm * K + kb + (t & 1) * 16);
                    #pragma unroll
                    for (int g = 0; g < 4; g++) {
                        f32x4 v = p[g];
                        av[4*g+0] = f2bf(v[0]); av[4*g+1] = f2bf(v[1]);
                        av[4*g+2] = f2bf(v[2]); av[4*g+3] = f2bf(v[3]);
                    }
                } else {
                    #pragma unroll
                    for (int g = 0; g < 16; g++) av[g] = 0;
                }
            } else {
                const int kbase = kb + (t & 1) * 16;
                #pragma unroll
                for (int i = 0; i < 16; i++) {
                    int k = kbase + i;
                    int ic = k / 9;
                    int tap = k - ic * 9;
                    int ky = tap / 3;
                    int kx = tap - ky * 3;
                    float v = 0.f;
                    if (MODE == 1) {
                        int iy = oy * 2 - 1 + ky, ix = ox * 2 - 1 + kx;
                        if (mv && (unsigned)iy < (unsigned)IH && (unsigned)ix < (unsigned)IW)
                            v = inb[((size_t)ic * IH + iy) * IW + ix];
                    } else {
                        int ty = oy + P - ky, tx = ox + P - kx;
                        if (mv && ty >= 0 && tx >= 0 && !(ty & 1) && !(tx & 1)) {
                            int iy = ty >> 1, ix = tx >> 1;
                            if (iy < IH && ix < IW)
                                v = inb[((size_t)ic * IH + iy) * IW + ix];
                        }
                    }
                    av[i] = f2bf(v);
                }
            }
            unsigned q[8];
            #pragma unroll
            for (int g = 0; g < 8; g++)
                q[g] = (unsigned)av[2*g] | ((unsigned)av[2*g+1] << 16);
            *(uint4*)&As[((akh    ) * BM + am) * 8] = make_uint4(q[0], q[1], q[2], q[3]);
            *(uint4*)&As[((akh + 1) * BM + am) * 8] = make_uint4(q[4], q[5], q[6], q[7]);
        }
        // ---- stage B (bf16 source [N][K]) ----
        if (b_act) {
            uint4 w0 = make_uint4(0,0,0,0), w1 = make_uint4(0,0,0,0);
            if (b_inr) {
                const uint4* p = (const uint4*)(Bw + (size_t)b_gn * K + kb + (t & 1) * 16);
                w0 = p[0]; w1 = p[1];
            }
            *(uint4*)&Bs[((bkh    ) * BN + bn_) * 8] = w0;
            *(uint4*)&Bs[((bkh + 1) * BN + bn_) * 8] = w1;
        }
        __syncthreads();
        // ---- fragments + MFMA ----
        bf16x8 af[RM], bfr[RN];
        #pragma unroll
        for (int i = 0; i < RM; i++)
            af[i] = *(const bf16x8*)&As[((size_t)(quad * BM + wm * (BM / 2) + i * 16 + lm)) * 8];
        #pragma unroll
        for (int j = 0; j < RN; j++)
            bfr[j] = *(const bf16x8*)&Bs[((size_t)(quad * BN + wn * (BN / 2) + j * 16 + lm)) * 8];
        #pragma unroll
        for (int i = 0; i < RM; i++)
            #pragma unroll
            for (int j = 0; j < RN; j++)
                acc[i][j] = __builtin_amdgcn_mfma_f32_16x16x32_bf16(af[i], bfr[j], acc[i][j], 0, 0, 0);
        __syncthreads();
    }

    // ---- epilogue ----
    const int n_base = nt * BN + wn * (BN / 2);
    const int m_base = mt * BM + wm * (BM / 2);
    if constexpr (MODE == 0) {
        #pragma unroll
        for (int i = 0; i < RM; i++) {
            #pragma unroll
            for (int j = 0; j < RN; j++) {
                int n = n_base + j * 16 + lm;
                if (n >= N) continue;
                float bv = (!SPLIT && bias != nullptr) ? bias[n] : 0.f;
                #pragma unroll
                for (int r = 0; r < 4; r++) {
                    int m = m_base + i * 16 + quad * 4 + r;
                    if (m >= M) continue;
                    size_t o = (size_t)m * N + n;
                    if (SPLIT) atomicAdd(&out[o], acc[i][j][r]);
                    else       out[o] = acc[i][j][r] + bv;
                }
            }
        }
    } else {
        const int ohw = OH * OW;
        #pragma unroll
        for (int i = 0; i < RM; i++) {
            int m0 = m_base + i * 16 + quad * 4;
            #pragma unroll
            for (int j = 0; j < RN; j++) {
                int n = n_base + j * 16 + lm;
                if (n >= N) continue;
                float bv = bias[n];
                if constexpr (MODE == 1) {
                    // OHW % 4 == 0 and m0 % 4 == 0: float4 store, same image
                    if (m0 < M) {
                        int bb = m0 / ohw, pix = m0 - bb * ohw;
                        f32x4 v;
                        #pragma unroll
                        for (int r = 0; r < 4; r++) {
                            float x = acc[i][j][r] + bv;
                            v[r] = LEAKY ? (x >= 0.f ? x : 0.01f * x) : x;
                        }
                        *(f32x4*)(out + ((size_t)bb * N + n) * ohw + pix) = v;
                    }
                } else {
                    #pragma unroll
                    for (int r = 0; r < 4; r++) {
                        int m = m0 + r;
                        if (m >= M) continue;
                        int bb = m / ohw, pix = m - bb * ohw;
                        out[((size_t)bb * N + n) * ohw + pix] = acc[i][j][r] + bv;
                    }
                }
            }
        }
    }
}

// ================= weight preprocessing =================
__global__ __launch_bounds__(256)
void cvt_copy(const float* __restrict__ in, unsigned short* __restrict__ out, int n4) {
    int i = blockIdx.x * 256 + threadIdx.x;
    if (i >= n4) return;
    f32x4 v = ((const f32x4*)in)[i];
    uint2 u;
    u.x = (unsigned)f2bf(v[0]) | ((unsigned)f2bf(v[1]) << 16);
    u.y = (unsigned)f2bf(v[2]) | ((unsigned)f2bf(v[3]) << 16);
    ((uint2*)out)[i] = u;
}

// out[c][r] = bf16(in[r][c]); grid (C/32, R/32), R,C multiples of 32
__global__ __launch_bounds__(256)
void transpose_cvt(const float* __restrict__ in, unsigned short* __restrict__ out, int R, int C) {
    __shared__ float tl[32][33];
    int c0 = blockIdx.x * 32, r0 = blockIdx.y * 32;
    int tx = threadIdx.x & 31, ty = threadIdx.x >> 5;
    #pragma unroll
    for (int l = 0; l < 4; l++)
        tl[ty + 8 * l][tx] = in[(size_t)(r0 + ty + 8 * l) * C + c0 + tx];
    __syncthreads();
    #pragma unroll
    for (int l = 0; l < 4; l++)
        out[(size_t)(c0 + ty + 8 * l) * R + r0 + tx] = f2bf(tl[tx][ty + 8 * l]);
}

// convT w [CIN][OC][3][3] -> bf16 [OC][CIN*9]
__global__ __launch_bounds__(256)
void permute_cvt_ctw(const float* __restrict__ in, unsigned short* __restrict__ out,
                     int CIN, int OC) {
    int idx = blockIdx.x * 256 + threadIdx.x;
    int total = CIN * OC * 9;
    if (idx >= total) return;
    int K9 = CIN * 9;
    int oc = idx / K9; int r = idx - oc * K9;
    int ic = r / 9;    int tap = r - ic * 9;
    out[idx] = f2bf(in[((size_t)ic * OC + oc) * 9 + tap]);
}

// ================= non-GEMM kernels =================
template<int CIN, int IH, int IW, int OH, int OW>
__global__ __launch_bounds__(256)
void conv3x3_s2_p1_leaky(const float* __restrict__ in, const float* __restrict__ w,
                         const float* __restrict__ bias, float* __restrict__ out,
                         int B, int OC) {
    int idx = blockIdx.x * blockDim.x + threadIdx.x;
    int total = B * OC * OH * OW;
    if (idx >= total) return;
    int ox = idx % OW; int t = idx / OW;
    int oy = t % OH;   t /= OH;
    int oc = t % OC;   int b = t / OC;
    int iy0 = oy * 2 - 1, ix0 = ox * 2 - 1;
    float acc = bias[oc];
    const float* inb = in + (size_t)b * CIN * IH * IW;
    const float* wb  = w  + (size_t)oc * CIN * 9;
    for (int ic = 0; ic < CIN; ic++) {
        const float* ip = inb + (size_t)ic * IH * IW;
        const float* wp = wb + ic * 9;
        #pragma unroll
        for (int ky = 0; ky < 3; ky++) {
            int iy = iy0 + ky;
            if (iy < 0 || iy >= IH) continue;
            #pragma unroll
            for (int kx = 0; kx < 3; kx++) {
                int ix = ix0 + kx;
                if (ix < 0 || ix >= IW) continue;
                acc = fmaf(ip[iy * IW + ix], wp[ky * 3 + kx], acc);
            }
        }
    }
    out[idx] = acc >= 0.f ? acc : 0.01f * acc;
}

__global__ __launch_bounds__(256)
void bn_inplace(float* __restrict__ data, int C, int B, int HW) {
    int c = blockIdx.x;
    int count = B * HW;
    __shared__ double ssum[256];
    __shared__ double ssq[256];
    double s = 0.0, q = 0.0;
    for (int i = threadIdx.x; i < count; i += 256) {
        int b = i / HW, p = i % HW;
        float v = data[((size_t)(b * C + c)) * HW + p];
        s += v; q += (double)v * (double)v;
    }
    ssum[threadIdx.x] = s; ssq[threadIdx.x] = q;
    __syncthreads();
    for (int off = 128; off > 0; off >>= 1) {
        if ((int)threadIdx.x < off) {
            ssum[threadIdx.x] += ssum[threadIdx.x + off];
            ssq[threadIdx.x]  += ssq[threadIdx.x + off];
        }
        __syncthreads();
    }
    __shared__ float smean, sinv;
    if (threadIdx.x == 0) {
        double mean = ssum[0] / count;
        double var  = ssq[0] / count - mean * mean;
        smean = (float)mean;
        sinv  = (float)(1.0 / sqrt(var + 1e-5));
    }
    __syncthreads();
    float mean = smean, inv = sinv;
    for (int i = threadIdx.x; i < count; i += 256) {
        int b = i / HW, p = i % HW;
        size_t o = ((size_t)(b * C + c)) * HW + p;
        data[o] = (data[o] - mean) * inv;
    }
}

__global__ __launch_bounds__(256)
void finalize_relu(const float* __restrict__ acc, const float* __restrict__ bias,
                   float* __restrict__ out) {
    int i = blockIdx.x * blockDim.x + threadIdx.x;
    if (i >= 100 * 800) return;
    float v = acc[i] + bias[i % 800];
    out[i] = fmaxf(v, 0.f);
}

__global__ __launch_bounds__(256)
void dft_real(const float* __restrict__ eig, float* __restrict__ Yr) {
    __shared__ float se[800];
    __shared__ float ctab[800];
    int b = blockIdx.x;
    for (int i = threadIdx.x; i < 800; i += 256) {
        se[i] = eig[b * 800 + i];
        ctab[i] = (float)cos(6.283185307179586 * (double)i / 800.0);
    }
    __syncthreads();
    for (int oi = threadIdx.x; oi < 800; oi += 256) {
        int k1 = oi >> 3, k2 = oi & 7;
        int d1 = k1 * 8;
        int d2 = k2 * 100;
        float acc = 0.f;
        int p1 = 0;
        for (int n1 = 0; n1 < 100; n1++) {
            int p = p1;
            #pragma unroll
            for (int n2 = 0; n2 < 8; n2++) {
                acc = fmaf(se[n1 * 8 + n2], ctab[p], acc);
                p += d2; if (p >= 800) p -= 800;
            }
            p1 += d1; if (p1 >= 800) p1 -= 800;
        }
        Yr[b * 800 + oi] = acc;
    }
}

__global__ __launch_bounds__(256)
void build_C4(const float* __restrict__ Yr, float* __restrict__ C) {
    int idx = blockIdx.x * 256 + threadIdx.x;
    if (idx >= 100 * 800 * 200) return;
    int j4 = (idx % 200) * 4; int tt = idx / 200;
    int i = tt % 800;         int b = tt / 800;
    const float* y = Yr + b * 800;
    f32x4 v;
    #pragma unroll
    for (int r = 0; r < 4; r++) {
        int k = i - (j4 + r);
        k += (k >> 31) & 800;
        v[r] = y[k] * 0.035355339059327376f;
    }
    ((f32x4*)C)[idx] = v;
}

__global__ __launch_bounds__(256)
void convT3x3(const float* __restrict__ in, const float* __restrict__ w,
              const float* __restrict__ bias, float* __restrict__ out,
              int B, int CIN, int IH, int IW, int OC, int OH, int OW, int S, int P) {
    int idx = blockIdx.x * blockDim.x + threadIdx.x;
    int total = B * OC * OH * OW;
    if (idx >= total) return;
    int ox = idx % OW; int t = idx / OW;
    int oy = t % OH;   t /= OH;
    int oc = t % OC;   int b = t / OC;
    float acc = bias[oc];
    for (int ky = 0; ky < 3; ky++) {
        int ty = oy + P - ky;
        if (ty < 0 || (ty % S)) continue;
        int iy = ty / S; if (iy >= IH) continue;
        for (int kx = 0; kx < 3; kx++) {
            int tx = ox + P - kx;
            if (tx < 0 || (tx % S)) continue;
            int ix = tx / S; if (ix >= IW) continue;
            const float* ip = in + ((size_t)(b * CIN) * IH + iy) * IW + ix;
            const float* wp = w + (size_t)oc * 9 + ky * 3 + kx;
            float s = 0.f;
            for (int ic = 0; ic < CIN; ic++)
                s = fmaf(ip[(size_t)ic * IH * IW], wp[(size_t)ic * OC * 9], s);
            acc += s;
        }
    }
    out[idx] = acc;
}

extern "C" void kernel_launch(void* const* d_in, const int* in_sizes, int n_in,
                              void* d_out, int out_size, void* d_ws, size_t ws_size,
                              hipStream_t stream) {
    const float* x    = (const float*)d_in[0];
    const float* c1w  = (const float*)d_in[1];  const float* c1b = (const float*)d_in[2];
    const float* c2w  = (const float*)d_in[3];  const float* c2b = (const float*)d_in[4];
    const float* c3w  = (const float*)d_in[5];  const float* c3b = (const float*)d_in[6];
    const float* c4w  = (const float*)d_in[7];  const float* c4b = (const float*)d_in[8];
    const float* fcw  = (const float*)d_in[9];  const float* fcb = (const float*)d_in[10];
    const float* decw = (const float*)d_in[11]; const float* decb = (const float*)d_in[12];
    const float* t1w  = (const float*)d_in[13]; const float* t1b = (const float*)d_in[14];
    const float* t2w  = (const float*)d_in[15]; const float* t2b = (const float*)d_in[16];
    const float* t3w  = (const float*)d_in[17]; const float* t3b = (const float*)d_in[18];
    const float* t4w  = (const float*)d_in[19]; const float* t4b = (const float*)d_in[20];
    const float* t5w  = (const float*)d_in[21]; const float* t5b = (const float*)d_in[22];

    float* out = (float*)d_out;
    float* ws  = (float*)d_ws;

    float* d_final = out;
    float* Cmat    = out + 240100;
    float* eig     = out + 240100 + 64000000;

    // two ws regions, reused with manual lifetime analysis (fits 109 MB)
    float* A  = ws;              // cap 13,107,200 floats
    float* Bp = ws + 13107200;   // cap 14,137,600 floats

    float* h1 = A;                  // (100,128,32,32) = 13,107,200 (A full)
    float* h2 = Bp;                 // (100,256,16,16) = 6,553,600
    float* h3 = A;                  // (100,1024,8,8)  = 6,553,600
    float* h4 = Bp;                 // (100,1024,4,4)  = 1,638,400
    float* facc = A;                // 80,000
    float* Yr  = A + 100000;        // 80,000
    float* d0  = Bp;                // (100,9216) = 921,600
    float* o1  = A;                 // (100,512,5,5)   = 1,280,000
    float* o2  = Bp;                // (100,256,11,11) = 3,097,600
    float* o3  = A;                 // (100,128,23,23) = 6,771,200
    float* o4  = Bp;                // (100,64,47,47)  = 14,137,600 (Bp full)

    unsigned short* W_c2  = (unsigned short*)(Bp + 6553600);  // 294,912 bf16
    unsigned short* W_c3  = (unsigned short*)(A  + 6600000);  // 2,359,296
    unsigned short* W_c4  = (unsigned short*)(Bp + 2000000);  // 9,437,184
    unsigned short* W_fc  = (unsigned short*)(Bp + 2000000);  // 13,107,200 (after conv4 done)
    unsigned short* W_dec = (unsigned short*)(Bp + 1000000);  // 7,372,800
    unsigned short* W_t1  = (unsigned short*)(Bp + 1000000);  // 4,718,592
    unsigned short* W_t2  = (unsigned short*)(Bp + 3200000);  // 1,179,648
    unsigned short* W_t3  = (unsigned short*)(A  + 6800000);  // 294,912
    unsigned short* W_t4  = (unsigned short*)(A  + 7000000);  // 73,728

    #define GRID(n) dim3(((n) + 255) / 256)

    // ---- encoder ----
    conv3x3_s2_p1_leaky<1, 64, 64, 32, 32><<<GRID(13107200), 256, 0, stream>>>(x, c1w, c1b, h1, 100, 128);
    bn_inplace<<<dim3(128), 256, 0, stream>>>(h1, 128, 100, 1024);

    cvt_copy<<<GRID(73728), 256, 0, stream>>>(c2w, W_c2, 73728);
    mfma_mm<1,128,128,true,false><<<dim3(200, 2), 256, 0, stream>>>(
        h1, W_c2, c2b, h2, 25600, 256, 1152, 128, 32, 32, 16, 16, 1, 0);
    bn_inplace<<<dim3(256), 256, 0, stream>>>(h2, 256, 100, 256);

    cvt_copy<<<GRID(589824), 256, 0, stream>>>(c3w, W_c3, 589824);
    mfma_mm<1,128,128,true,false><<<dim3(50, 8), 256, 0, stream>>>(
        h2, W_c3, c3b, h3, 6400, 1024, 2304, 256, 16, 16, 8, 8, 1, 0);
    bn_inplace<<<dim3(1024), 256, 0, stream>>>(h3, 1024, 100, 64);

    cvt_copy<<<GRID(2359296), 256, 0, stream>>>(c4w, W_c4, 2359296);
    mfma_mm<1,128,128,true,false><<<dim3(13, 8), 256, 0, stream>>>(
        h3, W_c4, c4b, h4, 1600, 1024, 9216, 1024, 8, 8, 4, 4, 1, 0);
    bn_inplace<<<dim3(1024), 256, 0, stream>>>(h4, 1024, 100, 16);

    // ---- fc (split-K z=8, atomic fp32) ----
    transpose_cvt<<<dim3(25, 512), 256, 0, stream>>>(fcw, W_fc, 16384, 800);
    hipMemsetAsync(facc, 0, 80000 * sizeof(float), stream);
    mfma_mm<0,32,128,false,true><<<dim3(4, 7, 8), 256, 0, stream>>>(
        h4, W_fc, nullptr, facc, 100, 800, 16384, 0, 0, 0, 0, 0, 0, 2048);
    finalize_relu<<<GRID(80000), 256, 0, stream>>>(facc, fcb, eig);

    // ---- FFT block ----
    dft_real<<<dim3(100), 256, 0, stream>>>(eig, Yr);
    build_C4<<<GRID(16000000), 256, 0, stream>>>(Yr, Cmat);

    // ---- dec matmul ----
    transpose_cvt<<<dim3(288, 25), 256, 0, stream>>>(decw, W_dec, 800, 9216);
    mfma_mm<0,32,128,false,false><<<dim3(4, 72), 256, 0, stream>>>(
        Yr, W_dec, decb, d0, 100, 9216, 800, 0, 0, 0, 0, 0, 0, 0);

    // ---- decoder convT stack ----
    permute_cvt_ctw<<<GRID(4718592), 256, 0, stream>>>(t1w, W_t1, 1024, 512);
    mfma_mm<2,64,128,false,false><<<dim3(40, 4), 256, 0, stream>>>(
        d0, W_t1, t1b, o1, 2500, 512, 9216, 1024, 3, 3, 5, 5, 1, 0);

    permute_cvt_ctw<<<GRID(1179648), 256, 0, stream>>>(t2w, W_t2, 512, 256);
    mfma_mm<2,64,128,false,false><<<dim3(190, 2), 256, 0, stream>>>(
        o1, W_t2, t2b, o2, 12100, 256, 4608, 512, 5, 5, 11, 11, 0, 0);

    permute_cvt_ctw<<<GRID(294912), 256, 0, stream>>>(t3w, W_t3, 256, 128);
    mfma_mm<2,128,128,false,false><<<dim3(414, 1), 256, 0, stream>>>(
        o2, W_t3, t3b, o3, 52900, 128, 2304, 256, 11, 11, 23, 23, 0, 0);

    permute_cvt_ctw<<<GRID(73728), 256, 0, stream>>>(t4w, W_t4, 128, 64);
    mfma_mm<2,128,64,false,false><<<dim3(1726, 1), 256, 0, stream>>>(
        o3, W_t4, t4b, o4, 220900, 64, 1152, 128, 23, 23, 47, 47, 0, 0);

    convT3x3<<<GRID(240100), 256, 0, stream>>>(o4, t5w, t5b, d_final, 100, 64, 47, 47, 1, 49, 49, 1, 0);

    #undef GRID
}

// Round 4
// 3640.206 us; speedup vs baseline: 16.4254x; 1.0791x over previous
//
#include <hip/hip_runtime.h>
#include <math.h>

typedef __attribute__((ext_vector_type(8))) short bf16x8;
typedef __attribute__((ext_vector_type(4))) float f32x4;

__device__ __forceinline__ unsigned short f2bf(float f) {
    unsigned u = __builtin_bit_cast(unsigned, f);
    u += 0x7FFFu + ((u >> 16) & 1u);   // RNE
    return (unsigned short)(u >> 16);
}

// ================= MFMA implicit-GEMM (MODE 0 = plain GEMM, MODE 1 = conv3x3 s2 p1) ==========
// A fp32; Bw bf16 [N][K]. 256 thr = 4 waves (2x2); mfma 16x16x32 bf16.
// LDS [k/8][row][8] halfwords. Bias added by blockIdx.z==0 (works split & non-split).
template<int MODE, int BM, int BN, bool SPLIT>
__global__ __launch_bounds__(256, 2)
void mfma_mm(const float* __restrict__ Af, const unsigned short* __restrict__ Bw,
             const float* __restrict__ bias, float* __restrict__ out,
             int M, int N, int K,
             int CIN, int IH, int IW, int OH, int OW, int zchunk)
{
    constexpr int RM = BM / 32, RN = BN / 32;
    __shared__ unsigned short As[4 * BM * 8];
    __shared__ unsigned short Bs[4 * BN * 8];
    const int t = threadIdx.x;
    const int lane = t & 63;
    const int wave = t >> 6;
    const int lm = lane & 15, quad = lane >> 4;
    const int wm = wave & 1, wn = wave >> 1;
    const int mt = blockIdx.x, nt = blockIdx.y;
    int k0 = 0, kend = K;
    if (SPLIT) { k0 = blockIdx.z * zchunk; kend = k0 + zchunk; }

    const int am  = t >> 1;
    const int akh = (t & 1) * 2;
    const bool a_act = am < BM;
    const int a_gm = mt * BM + am;
    int oy = 0, ox = 0; bool mv = false;
    const float* inb = Af;
    if (MODE == 1) {
        mv = a_act && (a_gm < M);
        int ohw = OH * OW;
        int bb = mv ? a_gm / ohw : 0;
        int rr = a_gm - bb * ohw;
        oy = rr / OW; ox = rr - oy * OW;
        inb = Af + (size_t)bb * CIN * IH * IW;
    }
    const int bn_ = t >> 1;
    const int bkh = (t & 1) * 2;
    const bool b_act = bn_ < BN;
    const int b_gn = nt * BN + bn_;
    const bool b_inr = b_act && (b_gn < N);

    f32x4 acc[RM][RN];
    #pragma unroll
    for (int i = 0; i < RM; i++)
        #pragma unroll
        for (int j = 0; j < RN; j++) acc[i][j] = (f32x4){0.f, 0.f, 0.f, 0.f};

    for (int kb = k0; kb < kend; kb += 32) {
        if (a_act) {
            unsigned short av[16];
            if (MODE == 0) {
                if (a_gm < M) {
                    const f32x4* p = (const f32x4*)(Af + (size_t)a_gm * K + kb + (t & 1) * 16);
                    #pragma unroll
                    for (int g = 0; g < 4; g++) {
                        f32x4 v = p[g];
                        av[4*g+0] = f2bf(v[0]); av[4*g+1] = f2bf(v[1]);
                        av[4*g+2] = f2bf(v[2]); av[4*g+3] = f2bf(v[3]);
                    }
                } else {
                    #pragma unroll
                    for (int g = 0; g < 16; g++) av[g] = 0;
                }
            } else {
                const int kbase = kb + (t & 1) * 16;
                #pragma unroll
                for (int i = 0; i < 16; i++) {
                    int k = kbase + i;
                    int ic = k / 9;
                    int tap = k - ic * 9;
                    int ky = tap / 3;
                    int kx = tap - ky * 3;
                    float v = 0.f;
                    int iy = oy * 2 - 1 + ky, ix = ox * 2 - 1 + kx;
                    if (mv && (unsigned)iy < (unsigned)IH && (unsigned)ix < (unsigned)IW)
                        v = inb[((size_t)ic * IH + iy) * IW + ix];
                    av[i] = f2bf(v);
                }
            }
            unsigned q[8];
            #pragma unroll
            for (int g = 0; g < 8; g++)
                q[g] = (unsigned)av[2*g] | ((unsigned)av[2*g+1] << 16);
            *(uint4*)&As[((akh    ) * BM + am) * 8] = make_uint4(q[0], q[1], q[2], q[3]);
            *(uint4*)&As[((akh + 1) * BM + am) * 8] = make_uint4(q[4], q[5], q[6], q[7]);
        }
        if (b_act) {
            uint4 w0 = make_uint4(0,0,0,0), w1 = make_uint4(0,0,0,0);
            if (b_inr) {
                const uint4* p = (const uint4*)(Bw + (size_t)b_gn * K + kb + (t & 1) * 16);
                w0 = p[0]; w1 = p[1];
            }
            *(uint4*)&Bs[((bkh    ) * BN + bn_) * 8] = w0;
            *(uint4*)&Bs[((bkh + 1) * BN + bn_) * 8] = w1;
        }
        __syncthreads();
        bf16x8 af[RM], bfr[RN];
        #pragma unroll
        for (int i = 0; i < RM; i++)
            af[i] = *(const bf16x8*)&As[((size_t)(quad * BM + wm * (BM / 2) + i * 16 + lm)) * 8];
        #pragma unroll
        for (int j = 0; j < RN; j++)
            bfr[j] = *(const bf16x8*)&Bs[((size_t)(quad * BN + wn * (BN / 2) + j * 16 + lm)) * 8];
        #pragma unroll
        for (int i = 0; i < RM; i++)
            #pragma unroll
            for (int j = 0; j < RN; j++)
                acc[i][j] = __builtin_amdgcn_mfma_f32_16x16x32_bf16(af[i], bfr[j], acc[i][j], 0, 0, 0);
        __syncthreads();
    }

    const int n_base = nt * BN + wn * (BN / 2);
    const int m_base = mt * BM + wm * (BM / 2);
    if constexpr (MODE == 0) {
        #pragma unroll
        for (int j = 0; j < RN; j++) {
            int n = n_base + j * 16 + lm;
            if (n >= N) continue;
            float bv = (bias != nullptr && blockIdx.z == 0) ? bias[n] : 0.f;
            #pragma unroll
            for (int i = 0; i < RM; i++) {
                #pragma unroll
                for (int r = 0; r < 4; r++) {
                    int m = m_base + i * 16 + quad * 4 + r;
                    if (m >= M) continue;
                    size_t o = (size_t)m * N + n;
                    if (SPLIT) atomicAdd(&out[o], acc[i][j][r] + bv);
                    else       out[o] = acc[i][j][r] + bv;
                }
            }
        }
    } else {
        const int ohw = OH * OW;
        #pragma unroll
        for (int i = 0; i < RM; i++) {
            int m0 = m_base + i * 16 + quad * 4;
            if (m0 >= M) continue;
            int bb = m0 / ohw, pix = m0 - bb * ohw;
            #pragma unroll
            for (int j = 0; j < RN; j++) {
                int n = n_base + j * 16 + lm;
                if (n >= N) continue;
                float bv = (bias != nullptr && blockIdx.z == 0) ? bias[n] : 0.f;
                if (SPLIT) {
                    #pragma unroll
                    for (int r = 0; r < 4; r++)
                        atomicAdd(&out[((size_t)bb * N + n) * ohw + pix + r], acc[i][j][r] + bv);
                } else {
                    f32x4 v;
                    #pragma unroll
                    for (int r = 0; r < 4; r++) v[r] = acc[i][j][r] + bv;
                    *(f32x4*)(out + ((size_t)bb * N + n) * ohw + pix) = v;  // ohw%4==0, m0%4==0
                }
            }
        }
    }
}

// ================= class-decomposed convT (stride 2) implicit GEMM =================
// Output parity class (cy,cx); T valid taps; K = CIN*T; Bw bf16 [OC][CIN*T].
// A gather: iy = oy' + dy[ti], ix = ox' + dx[ti] (parity guaranteed, range-checked only).
template<int T, int BM, int BN, bool SPLIT>
__global__ __launch_bounds__(256, 2)
void mfma_ct(const float* __restrict__ Af, const unsigned short* __restrict__ Bw,
             const float* __restrict__ bias, float* __restrict__ out,
             int M, int N, int K,
             int IH, int IW, int OH, int OW, int OHc, int OWc,
             int cy, int cx, int dyp, int dxp, int zchunk)
{
    constexpr int RM = BM / 32, RN = BN / 32;
    constexpr int LG = (T == 1) ? 0 : (T == 2) ? 1 : 2;
    __shared__ unsigned short As[4 * BM * 8];
    __shared__ unsigned short Bs[4 * BN * 8];
    const int t = threadIdx.x;
    const int lane = t & 63;
    const int wave = t >> 6;
    const int lm = lane & 15, quad = lane >> 4;
    const int wm = wave & 1, wn = wave >> 1;
    const int mt = blockIdx.x, nt = blockIdx.y;
    const int k0 = SPLIT ? blockIdx.z * zchunk : 0;
    const int kend = SPLIT ? k0 + zchunk : K;
    const int CIN = K >> LG;
    const int IHW = IH * IW;

    const int am  = t >> 1;
    const int akh = (t & 1) * 2;
    const int kofs = (t & 1) * 16;
    const bool a_act = am < BM;
    const int a_gm = mt * BM + am;
    const bool mv = a_act && (a_gm < M);
    const int ohwc = OHc * OWc;
    int bb = mv ? a_gm / ohwc : 0;
    int rr = a_gm - bb * ohwc;
    int oyp = rr / OWc, oxp = rr - (rr / OWc) * OWc;
    const float* inb = Af + (size_t)bb * CIN * IHW;
    int   off_t[T];
    bool  val_t[T];
    #pragma unroll
    for (int ti = 0; ti < T; ti++) {
        int dy = (int)(signed char)((dyp >> (8 * ti)) & 255);
        int dx = (int)(signed char)((dxp >> (8 * ti)) & 255);
        int iy = oyp + dy, ix = oxp + dx;
        val_t[ti] = mv && (unsigned)iy < (unsigned)IH && (unsigned)ix < (unsigned)IW;
        off_t[ti] = val_t[ti] ? iy * IW + ix : 0;
    }

    const int bn_ = t >> 1;
    const int bkh = (t & 1) * 2;
    const bool b_act = bn_ < BN;
    const int b_gn = nt * BN + bn_;
    const bool b_inr = b_act && (b_gn < N);

    f32x4 acc[RM][RN];
    #pragma unroll
    for (int i = 0; i < RM; i++)
        #pragma unroll
        for (int j = 0; j < RN; j++) acc[i][j] = (f32x4){0.f, 0.f, 0.f, 0.f};

    for (int kb = k0; kb < kend; kb += 32) {
        if (a_act) {
            const int icb = (kb + kofs) >> LG;
            unsigned short av[16];
            #pragma unroll
            for (int i = 0; i < 16; i++) {
                const int ti = i & (T - 1);
                int ic = icb + (i >> LG);
                float v = val_t[ti] ? inb[(size_t)ic * IHW + off_t[ti]] : 0.f;
                av[i] = f2bf(v);
            }
            unsigned q[8];
            #pragma unroll
            for (int g = 0; g < 8; g++)
                q[g] = (unsigned)av[2*g] | ((unsigned)av[2*g+1] << 16);
            *(uint4*)&As[((akh    ) * BM + am) * 8] = make_uint4(q[0], q[1], q[2], q[3]);
            *(uint4*)&As[((akh + 1) * BM + am) * 8] = make_uint4(q[4], q[5], q[6], q[7]);
        }
        if (b_act) {
            uint4 w0 = make_uint4(0,0,0,0), w1 = make_uint4(0,0,0,0);
            if (b_inr) {
                const uint4* p = (const uint4*)(Bw + (size_t)b_gn * K + kb + kofs);
                w0 = p[0]; w1 = p[1];
            }
            *(uint4*)&Bs[((bkh    ) * BN + bn_) * 8] = w0;
            *(uint4*)&Bs[((bkh + 1) * BN + bn_) * 8] = w1;
        }
        __syncthreads();
        bf16x8 af[RM], bfr[RN];
        #pragma unroll
        for (int i = 0; i < RM; i++)
            af[i] = *(const bf16x8*)&As[((size_t)(quad * BM + wm * (BM / 2) + i * 16 + lm)) * 8];
        #pragma unroll
        for (int j = 0; j < RN; j++)
            bfr[j] = *(const bf16x8*)&Bs[((size_t)(quad * BN + wn * (BN / 2) + j * 16 + lm)) * 8];
        #pragma unroll
        for (int i = 0; i < RM; i++)
            #pragma unroll
            for (int j = 0; j < RN; j++)
                acc[i][j] = __builtin_amdgcn_mfma_f32_16x16x32_bf16(af[i], bfr[j], acc[i][j], 0, 0, 0);
        __syncthreads();
    }

    const int n_base = nt * BN + wn * (BN / 2);
    const int m_base = mt * BM + wm * (BM / 2);
    const int OHW = OH * OW;
    int   nj[RN]; float bvj[RN];
    #pragma unroll
    for (int j = 0; j < RN; j++) {
        nj[j] = n_base + j * 16 + lm;
        bvj[j] = (nj[j] < N && bias != nullptr && blockIdx.z == 0) ? bias[nj[j]] : 0.f;
    }
    #pragma unroll
    for (int i = 0; i < RM; i++) {
        #pragma unroll
        for (int r = 0; r < 4; r++) {
            int m = m_base + i * 16 + quad * 4 + r;
            if (m >= M) continue;
            int b2 = m / ohwc; int r2 = m - b2 * ohwc;
            int oy = r2 / OWc, ox = r2 - (r2 / OWc) * OWc;
            size_t pbase = (size_t)b2 * N * OHW + (size_t)(2 * oy + cy) * OW + (2 * ox + cx);
            #pragma unroll
            for (int j = 0; j < RN; j++) {
                if (nj[j] >= N) continue;
                size_t o = pbase + (size_t)nj[j] * OHW;
                if (SPLIT) atomicAdd(&out[o], acc[i][j][r] + bvj[j]);
                else       out[o] = acc[i][j][r] + bvj[j];
            }
        }
    }
}

// ================= weight preprocessing =================
__global__ __launch_bounds__(256)
void cvt_copy(const float* __restrict__ in, unsigned short* __restrict__ out, int n4) {
    int i = blockIdx.x * 256 + threadIdx.x;
    if (i >= n4) return;
    f32x4 v = ((const f32x4*)in)[i];
    uint2 u;
    u.x = (unsigned)f2bf(v[0]) | ((unsigned)f2bf(v[1]) << 16);
    u.y = (unsigned)f2bf(v[2]) | ((unsigned)f2bf(v[3]) << 16);
    ((uint2*)out)[i] = u;
}

__global__ __launch_bounds__(256)
void transpose_cvt(const float* __restrict__ in, unsigned short* __restrict__ out, int R, int C) {
    __shared__ float tl[32][33];
    int c0 = blockIdx.x * 32, r0 = blockIdx.y * 32;
    int tx = threadIdx.x & 31, ty = threadIdx.x >> 5;
    #pragma unroll
    for (int l = 0; l < 4; l++)
        tl[ty + 8 * l][tx] = in[(size_t)(r0 + ty + 8 * l) * C + c0 + tx];
    __syncthreads();
    #pragma unroll
    for (int l = 0; l < 4; l++)
        out[(size_t)(c0 + ty + 8 * l) * R + r0 + tx] = f2bf(tl[tx][ty + 8 * l]);
}

// convT w [CIN][OC][3][3] -> per-class bf16 [OC][CIN*T]; grid.y = class
__global__ __launch_bounds__(256)
void prep_ctw(const float* __restrict__ in, unsigned short* __restrict__ out,
              int CIN, int OC, int4 Tv, int4 offv, int4 kyv, int4 kxv) {
    int c = blockIdx.y;
    int Tarr[4]  = {Tv.x, Tv.y, Tv.z, Tv.w};
    int offarr[4]= {offv.x, offv.y, offv.z, offv.w};
    int kyarr[4] = {kyv.x, kyv.y, kyv.z, kyv.w};
    int kxarr[4] = {kxv.x, kxv.y, kxv.z, kxv.w};
    int T = Tarr[c];
    int total = OC * CIN * T;
    int idx = blockIdx.x * 256 + threadIdx.x;
    if (idx >= total) return;
    int lg = (T == 1) ? 0 : (T == 2) ? 1 : 2;
    int ti = idx & (T - 1);
    int q = idx >> lg;
    int ic = q % CIN;
    int oc = q / CIN;
    int ky = (kyarr[c] >> (8 * ti)) & 255;
    int kx = (kxarr[c] >> (8 * ti)) & 255;
    out[offarr[c] + idx] = f2bf(in[((size_t)ic * OC + oc) * 9 + ky * 3 + kx]);
}

// ================= non-GEMM kernels =================
// conv1 (CIN=1): raw conv + bias (leaky moved into bn_leaky)
__global__ __launch_bounds__(256)
void conv1_bias(const float* __restrict__ in, const float* __restrict__ w,
                const float* __restrict__ bias, float* __restrict__ out) {
    const int IH = 64, IW = 64, OH = 32, OW = 32, OC = 128;
    int idx = blockIdx.x * blockDim.x + threadIdx.x;
    if (idx >= 100 * OC * OH * OW) return;
    int ox = idx % OW; int t = idx / OW;
    int oy = t % OH;   t /= OH;
    int oc = t % OC;   int b = t / OC;
    int iy0 = oy * 2 - 1, ix0 = ox * 2 - 1;
    float acc = bias[oc];
    const float* ip = in + (size_t)b * IH * IW;
    const float* wp = w + oc * 9;
    #pragma unroll
    for (int ky = 0; ky < 3; ky++) {
        int iy = iy0 + ky;
        if (iy < 0 || iy >= IH) continue;
        #pragma unroll
        for (int kx = 0; kx < 3; kx++) {
            int ix = ix0 + kx;
            if (ix < 0 || ix >= IW) continue;
            acc = fmaf(ip[iy * IW + ix], wp[ky * 3 + kx], acc);
        }
    }
    out[idx] = acc;
}

// bn with fused leaky: y = (leaky(v) - mean)/sqrt(var+eps), stats over leaky(v)
__global__ __launch_bounds__(256)
void bn_leaky(float* __restrict__ data, int C, int B, int HW) {
    int c = blockIdx.x;
    int count = B * HW;
    __shared__ double ssum[256];
    __shared__ double ssq[256];
    double s = 0.0, q = 0.0;
    for (int i = threadIdx.x; i < count; i += 256) {
        int b = i / HW, p = i % HW;
        float v = data[((size_t)(b * C + c)) * HW + p];
        v = v >= 0.f ? v : 0.01f * v;
        s += v; q += (double)v * (double)v;
    }
    ssum[threadIdx.x] = s; ssq[threadIdx.x] = q;
    __syncthreads();
    for (int off = 128; off > 0; off >>= 1) {
        if ((int)threadIdx.x < off) {
            ssum[threadIdx.x] += ssum[threadIdx.x + off];
            ssq[threadIdx.x]  += ssq[threadIdx.x + off];
        }
        __syncthreads();
    }
    __shared__ float smean, sinv;
    if (threadIdx.x == 0) {
        double mean = ssum[0] / count;
        double var  = ssq[0] / count - mean * mean;
        smean = (float)mean;
        sinv  = (float)(1.0 / sqrt(var + 1e-5));
    }
    __syncthreads();
    float mean = smean, inv = sinv;
    for (int i = threadIdx.x; i < count; i += 256) {
        int b = i / HW, p = i % HW;
        size_t o = ((size_t)(b * C + c)) * HW + p;
        float v = data[o];
        v = v >= 0.f ? v : 0.01f * v;
        data[o] = (v - mean) * inv;
    }
}

__global__ __launch_bounds__(256)
void finalize_relu(const float* __restrict__ acc, const float* __restrict__ bias,
                   float* __restrict__ out) {
    int i = blockIdx.x * blockDim.x + threadIdx.x;
    if (i >= 100 * 800) return;
    float v = acc[i] + bias[i % 800];
    out[i] = fmaxf(v, 0.f);
}

__global__ __launch_bounds__(256)
void dft_real(const float* __restrict__ eig, float* __restrict__ Yr) {
    __shared__ float se[800];
    __shared__ float ctab[800];
    int b = blockIdx.x;
    for (int i = threadIdx.x; i < 800; i += 256) {
        se[i] = eig[b * 800 + i];
        ctab[i] = (float)cos(6.283185307179586 * (double)i / 800.0);
    }
    __syncthreads();
    for (int oi = threadIdx.x; oi < 800; oi += 256) {
        int k1 = oi >> 3, k2 = oi & 7;
        int d1 = k1 * 8;
        int d2 = k2 * 100;
        float acc = 0.f;
        int p1 = 0;
        for (int n1 = 0; n1 < 100; n1++) {
            int p = p1;
            #pragma unroll
            for (int n2 = 0; n2 < 8; n2++) {
                acc = fmaf(se[n1 * 8 + n2], ctab[p], acc);
                p += d2; if (p >= 800) p -= 800;
            }
            p1 += d1; if (p1 >= 800) p1 -= 800;
        }
        Yr[b * 800 + oi] = acc;
    }
}

__global__ __launch_bounds__(256)
void build_C4(const float* __restrict__ Yr, float* __restrict__ C) {
    int idx = blockIdx.x * 256 + threadIdx.x;
    if (idx >= 100 * 800 * 200) return;
    int j4 = (idx % 200) * 4; int tt = idx / 200;
    int i = tt % 800;         int b = tt / 800;
    const float* y = Yr + b * 800;
    f32x4 v;
    #pragma unroll
    for (int r = 0; r < 4; r++) {
        int k = i - (j4 + r);
        k += (k >> 31) & 800;
        v[r] = y[k] * 0.035355339059327376f;
    }
    ((f32x4*)C)[idx] = v;
}

// ct5: stride-1 convT, OC=1, naive
__global__ __launch_bounds__(256)
void convT3x3_s1(const float* __restrict__ in, const float* __restrict__ w,
                 const float* __restrict__ bias, float* __restrict__ out,
                 int B, int CIN, int IH, int IW, int OH, int OW) {
    int idx = blockIdx.x * blockDim.x + threadIdx.x;
    int total = B * OH * OW;
    if (idx >= total) return;
    int ox = idx % OW; int t = idx / OW;
    int oy = t % OH;   int b = t / OH;
    float acc = bias[0];
    for (int ky = 0; ky < 3; ky++) {
        int iy = oy - ky;
        if ((unsigned)iy >= (unsigned)IH) continue;
        for (int kx = 0; kx < 3; kx++) {
            int ix = ox - kx;
            if ((unsigned)ix >= (unsigned)IW) continue;
            const float* ip = in + ((size_t)(b * CIN) * IH + iy) * IW + ix;
            const float* wp = w + ky * 3 + kx;
            float s = 0.f;
            for (int ic = 0; ic < CIN; ic++)
                s = fmaf(ip[(size_t)ic * IH * IW], wp[(size_t)ic * 9], s);
            acc += s;
        }
    }
    out[idx] = acc;
}

// ================= host helpers =================
static void ct_class_params(int P, int cy, int cx, int OH, int OW,
                            int& T, int& OHc, int& OWc, int& kyp, int& kxp, int& dyp, int& dxp) {
    int kys[2], dys[2], nky = 0;
    for (int ky = 0; ky < 3; ky++)
        if (((cy + P + ky) & 1) == 0) { kys[nky] = ky; dys[nky] = (cy + P - ky) / 2; nky++; }
    int kxs[2], dxs[2], nkx = 0;
    for (int kx = 0; kx < 3; kx++)
        if (((cx + P + kx) & 1) == 0) { kxs[nkx] = kx; dxs[nkx] = (cx + P - kx) / 2; nkx++; }
    T = nky * nkx;
    OHc = (OH - cy + 1) >> 1;
    OWc = (OW - cx + 1) >> 1;
    kyp = kxp = dyp = dxp = 0;
    int ti = 0;
    for (int a = 0; a < nky; a++)
        for (int b = 0; b < nkx; b++, ti++) {
            kyp |= kys[a] << (8 * ti);
            kxp |= kxs[b] << (8 * ti);
            dyp |= (dys[a] & 255) << (8 * ti);
            dxp |= (dxs[b] & 255) << (8 * ti);
        }
}

template<int BM, int BN, bool SPLIT>
static void run_ct_layer(hipStream_t s, const float* in, const float* wsrc, unsigned short* wbuf,
                         const float* bias, float* outp,
                         int CIN, int OC, int IH, int IW, int OH, int OW, int P, const int* zs) {
    // prep all 4 classes in one launch
    int T[4], OHc[4], OWc[4], kyp[4], kxp[4], dyp[4], dxp[4], off[4];
    int o = 0;
    for (int c = 0; c < 4; c++) {
        ct_class_params(P, c >> 1, c & 1, OH, OW, T[c], OHc[c], OWc[c], kyp[c], kxp[c], dyp[c], dxp[c]);
        off[c] = o;
        o += OC * CIN * T[c];
    }
    int maxtot = OC * CIN * 4;
    prep_ctw<<<dim3((maxtot + 255) / 256, 4), 256, 0, s>>>(
        wsrc, wbuf, CIN, OC,
        make_int4(T[0], T[1], T[2], T[3]), make_int4(off[0], off[1], off[2], off[3]),
        make_int4(kyp[0], kyp[1], kyp[2], kyp[3]), make_int4(kxp[0], kxp[1], kxp[2], kxp[3]));
    for (int c = 0; c < 4; c++) {
        int M = 100 * OHc[c] * OWc[c];
        int K = CIN * T[c];
        int z = zs[c];
        int chunk = K / z;
        dim3 g((M + BM - 1) / BM, (OC + BN - 1) / BN, z);
        if (T[c] == 1)
            mfma_ct<1, BM, BN, SPLIT><<<g, 256, 0, s>>>(in, wbuf + off[c], bias, outp, M, OC, K,
                IH, IW, OH, OW, OHc[c], OWc[c], c >> 1, c & 1, dyp[c], dxp[c], chunk);
        else if (T[c] == 2)
            mfma_ct<2, BM, BN, SPLIT><<<g, 256, 0, s>>>(in, wbuf + off[c], bias, outp, M, OC, K,
                IH, IW, OH, OW, OHc[c], OWc[c], c >> 1, c & 1, dyp[c], dxp[c], chunk);
        else
            mfma_ct<4, BM, BN, SPLIT><<<g, 256, 0, s>>>(in, wbuf + off[c], bias, outp, M, OC, K,
                IH, IW, OH, OW, OHc[c], OWc[c], c >> 1, c & 1, dyp[c], dxp[c], chunk);
    }
}

extern "C" void kernel_launch(void* const* d_in, const int* in_sizes, int n_in,
                              void* d_out, int out_size, void* d_ws, size_t ws_size,
                              hipStream_t stream) {
    const float* x    = (const float*)d_in[0];
    const float* c1w  = (const float*)d_in[1];  const float* c1b = (const float*)d_in[2];
    const float* c2w  = (const float*)d_in[3];  const float* c2b = (const float*)d_in[4];
    const float* c3w  = (const float*)d_in[5];  const float* c3b = (const float*)d_in[6];
    const float* c4w  = (const float*)d_in[7];  const float* c4b = (const float*)d_in[8];
    const float* fcw  = (const float*)d_in[9];  const float* fcb = (const float*)d_in[10];
    const float* decw = (const float*)d_in[11]; const float* decb = (const float*)d_in[12];
    const float* t1w  = (const float*)d_in[13]; const float* t1b = (const float*)d_in[14];
    const float* t2w  = (const float*)d_in[15]; const float* t2b = (const float*)d_in[16];
    const float* t3w  = (const float*)d_in[17]; const float* t3b = (const float*)d_in[18];
    const float* t4w  = (const float*)d_in[19]; const float* t4b = (const float*)d_in[20];
    const float* t5w  = (const float*)d_in[21]; const float* t5b = (const float*)d_in[22];

    float* out = (float*)d_out;
    float* ws  = (float*)d_ws;

    float* d_final = out;
    float* Cmat    = out + 240100;
    float* eig     = out + 240100 + 64000000;

    // two ws regions, manual lifetime analysis (fits 109 MB)
    float* A  = ws;              // cap 13,107,200 floats
    float* Bp = ws + 13107200;   // cap 14,137,600 floats

    float* h1 = A;                  // (100,128,32,32)
    float* h2 = Bp;                 // (100,256,16,16)
    float* h3 = A;                  // (100,1024,8,8)
    float* h4 = Bp;                 // (100,1024,4,4)
    float* facc = A;                // 80,000
    float* Yr  = A + 100000;        // 80,000
    float* d0  = Bp;                // (100,9216)
    float* o1  = A;                 // (100,512,5,5)
    float* o2  = Bp;                // (100,256,11,11)
    float* o3  = A;                 // (100,128,23,23)
    float* o4  = Bp;                // (100,64,47,47)

    unsigned short* W_c2  = (unsigned short*)(Bp + 6553600);
    unsigned short* W_c3  = (unsigned short*)(A  + 6600000);
    unsigned short* W_c4  = (unsigned short*)(Bp + 2000000);
    unsigned short* W_fc  = (unsigned short*)(Bp + 2000000);
    unsigned short* W_dec = (unsigned short*)(Bp + 1000000);
    unsigned short* W_t1  = (unsigned short*)(Bp + 1000000);
    unsigned short* W_t2  = (unsigned short*)(Bp + 3200000);
    unsigned short* W_t3  = (unsigned short*)(A  + 6800000);
    unsigned short* W_t4  = (unsigned short*)(A  + 7000000);

    #define GRID(n) dim3(((n) + 255) / 256)

    // ---- encoder ----
    conv1_bias<<<GRID(13107200), 256, 0, stream>>>(x, c1w, c1b, h1);
    bn_leaky<<<dim3(128), 256, 0, stream>>>(h1, 128, 100, 1024);

    cvt_copy<<<GRID(73728), 256, 0, stream>>>(c2w, W_c2, 73728);
    mfma_mm<1,128,64,false><<<dim3(200, 4), 256, 0, stream>>>(
        h1, W_c2, c2b, h2, 25600, 256, 1152, 128, 32, 32, 16, 16, 0);
    bn_leaky<<<dim3(256), 256, 0, stream>>>(h2, 256, 100, 256);

    cvt_copy<<<GRID(589824), 256, 0, stream>>>(c3w, W_c3, 589824);
    mfma_mm<1,128,64,false><<<dim3(50, 16), 256, 0, stream>>>(
        h2, W_c3, c3b, h3, 6400, 1024, 2304, 256, 16, 16, 8, 8, 0);
    bn_leaky<<<dim3(1024), 256, 0, stream>>>(h3, 1024, 100, 64);

    cvt_copy<<<GRID(2359296), 256, 0, stream>>>(c4w, W_c4, 2359296);
    hipMemsetAsync(h4, 0, 1638400 * sizeof(float), stream);
    mfma_mm<1,128,64,true><<<dim3(13, 16, 4), 256, 0, stream>>>(
        h3, W_c4, c4b, h4, 1600, 1024, 9216, 1024, 8, 8, 4, 4, 2304);
    bn_leaky<<<dim3(1024), 256, 0, stream>>>(h4, 1024, 100, 16);

    // ---- fc (split-K z=16) ----
    transpose_cvt<<<dim3(25, 512), 256, 0, stream>>>(fcw, W_fc, 16384, 800);
    hipMemsetAsync(facc, 0, 80000 * sizeof(float), stream);
    mfma_mm<0,32,128,true><<<dim3(4, 7, 16), 256, 0, stream>>>(
        h4, W_fc, nullptr, facc, 100, 800, 16384, 0, 0, 0, 0, 0, 1024);
    finalize_relu<<<GRID(80000), 256, 0, stream>>>(facc, fcb, eig);

    // ---- FFT block ----
    dft_real<<<dim3(100), 256, 0, stream>>>(eig, Yr);
    build_C4<<<GRID(16000000), 256, 0, stream>>>(Yr, Cmat);

    // ---- dec matmul ----
    transpose_cvt<<<dim3(288, 25), 256, 0, stream>>>(decw, W_dec, 800, 9216);
    mfma_mm<0,32,64,false><<<dim3(4, 144), 256, 0, stream>>>(
        Yr, W_dec, decb, d0, 100, 9216, 800, 0, 0, 0, 0, 0, 0);

    // ---- decoder convT stack (parity-decomposed) ----
    static const int zs1[4] = {4, 4, 4, 8};
    static const int zs2[4] = {4, 4, 4, 4};
    static const int zs3[4] = {2, 2, 2, 2};
    static const int zs4[4] = {1, 1, 1, 1};

    hipMemsetAsync(o1, 0, 1280000 * sizeof(float), stream);
    run_ct_layer<64,128,true>(stream, d0, t1w, W_t1, t1b, o1, 1024, 512, 3, 3, 5, 5, 1, zs1);

    hipMemsetAsync(o2, 0, 3097600 * sizeof(float), stream);
    run_ct_layer<64,128,true>(stream, o1, t2w, W_t2, t2b, o2, 512, 256, 5, 5, 11, 11, 0, zs2);

    hipMemsetAsync(o3, 0, 6771200 * sizeof(float), stream);
    run_ct_layer<64,128,true>(stream, o2, t3w, W_t3, t3b, o3, 256, 128, 11, 11, 23, 23, 0, zs3);

    run_ct_layer<128,64,false>(stream, o3, t4w, W_t4, t4b, o4, 128, 64, 23, 23, 47, 47, 0, zs4);

    convT3x3_s1<<<GRID(240100), 256, 0, stream>>>(o4, t5w, t5b, d_final, 100, 64, 47, 47, 49, 49);

    #undef GRID
}

// Round 5
// 1475.837 us; speedup vs baseline: 40.5137x; 2.4665x over previous
//
#include <hip/hip_runtime.h>
#include <math.h>

typedef __attribute__((ext_vector_type(8))) short bf16x8;
typedef __attribute__((ext_vector_type(4))) float f32x4;
typedef unsigned short u16;

__device__ __forceinline__ u16 f2bf(float f) {
    unsigned u = __builtin_bit_cast(unsigned, f);
    u += 0x7FFFu + ((u >> 16) & 1u);   // RNE
    return (u16)(u >> 16);
}
__device__ __forceinline__ float bf2f(u16 h) {
    unsigned u = ((unsigned)h) << 16;
    return __builtin_bit_cast(float, u);
}

// =====================================================================
// Unified MFMA GEMM.
// MODE 0: A = bf16 [M][K] rows            (fc, dec)
// MODE 1: A = im2col of bf16 NHWC input, conv3x3 s2 p1; k = tap*CIN+ic
// MODE 2: A = parity-class convT gather of bf16 NHWC; k = ti*CIN+ic
// OUT  0: bf16 NHWC conv (+bias)          1: fp32 atomic NHWC conv (+bias z0)
// OUT  2: bf16 NHWC ct (+bias)            3: fp32 atomic NHWC ct (+bias z0)
// OUT  4: fp32 atomic plain (no bias)     5: bf16 dec-permuted [m][hw][c] (+bias)
// 256 thr = 4 waves (2x2); wave tile (BM/2)x(BN/2); mfma 16x16x32 bf16.
// LDS [k/8][row][8] halfwords -> 16B-aligned ds_read_b128 frags.
// =====================================================================
template<int MODE, int OUT, int BM, int BN>
__global__ __launch_bounds__(256, 2)
void gemm(const u16* __restrict__ Abf, const u16* __restrict__ Bw,
          const float* __restrict__ bias, void* __restrict__ outv,
          int M, int N, int K, int lgC,
          int IH, int IW, int OH, int OW, int OHc, int OWc,
          int cy, int cx, int dyp, int dxp, int zchunk)
{
    constexpr int ANSEG = BM / 64, BNSEG = BN / 64;
    constexpr int RM = BM / 32, RN = BN / 32;
    __shared__ __align__(16) u16 As[4 * BM * 8];
    __shared__ __align__(16) u16 Bs[4 * BN * 8];
    const int t = threadIdx.x;
    const int lane = t & 63, wave = t >> 6;
    const int lm = lane & 15, quad = lane >> 4;
    const int wm = wave & 1, wn = wave >> 1;
    const int mt = blockIdx.x, nt = blockIdx.y;
    const int k0 = blockIdx.z * zchunk;
    const int kend = k0 + zchunk;

    // A staging map
    const int arow = (ANSEG == 2) ? (t >> 1) : (t >> 2);
    const int akb  = (ANSEG == 2) ? (t & 1) * 16 : (t & 3) * 8;
    const int a_gm = mt * BM + arow;
    const bool a_in = a_gm < M;
    int oy = 0, ox = 0, bimg = 0; bool mval = false;
    if (MODE == 1) {
        mval = a_in;
        int ohw = OH * OW;
        int g = a_in ? a_gm : 0;
        bimg = g / ohw; int r = g - bimg * ohw;
        oy = r / OW; ox = r - (r / OW) * OW;
    } else if (MODE == 2) {
        mval = a_in;
        int ohwc = OHc * OWc;
        int g = a_in ? a_gm : 0;
        bimg = g / ohwc; int r = g - bimg * ohwc;
        oy = r / OWc; ox = r - (r / OWc) * OWc;
    }
    // B staging map
    const int brow = (BNSEG == 2) ? (t >> 1) : (t >> 2);
    const int bkb  = (BNSEG == 2) ? (t & 1) * 16 : (t & 3) * 8;
    const int b_gn = nt * BN + brow;
    const bool b_in = b_gn < N;

    f32x4 acc[RM][RN];
    #pragma unroll
    for (int i = 0; i < RM; i++)
        #pragma unroll
        for (int j = 0; j < RN; j++) acc[i][j] = (f32x4){0.f, 0.f, 0.f, 0.f};

    for (int kb = k0; kb < kend; kb += 32) {
        #pragma unroll
        for (int s = 0; s < ANSEG; s++) {
            int kk = kb + akb + s * 8;
            uint4 v = make_uint4(0, 0, 0, 0);
            if (MODE == 0) {
                if (a_in) v = *(const uint4*)(Abf + (size_t)a_gm * K + kk);
            } else if (MODE == 1) {
                int tap = kk >> lgC;
                int ic = kk & ((1 << lgC) - 1);
                int ky = tap / 3, kx = tap - (tap / 3) * 3;
                int iy = oy * 2 - 1 + ky, ix = ox * 2 - 1 + kx;
                if (mval && (unsigned)iy < (unsigned)IH && (unsigned)ix < (unsigned)IW)
                    v = *(const uint4*)(Abf + ((((size_t)bimg * IH + iy) * IW + ix) << lgC) + ic);
            } else {
                int ti = kk >> lgC;
                int ic = kk & ((1 << lgC) - 1);
                int dy = (int)(signed char)((dyp >> (8 * ti)) & 255);
                int dx = (int)(signed char)((dxp >> (8 * ti)) & 255);
                int iy = oy + dy, ix = ox + dx;
                if (mval && (unsigned)iy < (unsigned)IH && (unsigned)ix < (unsigned)IW)
                    v = *(const uint4*)(Abf + ((((size_t)bimg * IH + iy) * IW + ix) << lgC) + ic);
            }
            *(uint4*)&As[(((akb >> 3) + s) * BM + arow) * 8] = v;
        }
        #pragma unroll
        for (int s = 0; s < BNSEG; s++) {
            int kk = kb + bkb + s * 8;
            uint4 v = make_uint4(0, 0, 0, 0);
            if (b_in) v = *(const uint4*)(Bw + (size_t)b_gn * K + kk);
            *(uint4*)&Bs[(((bkb >> 3) + s) * BN + brow) * 8] = v;
        }
        __syncthreads();
        bf16x8 af[RM], bfr[RN];
        #pragma unroll
        for (int i = 0; i < RM; i++)
            af[i] = *(const bf16x8*)&As[(size_t)(quad * BM + wm * (BM / 2) + i * 16 + lm) * 8];
        #pragma unroll
        for (int j = 0; j < RN; j++)
            bfr[j] = *(const bf16x8*)&Bs[(size_t)(quad * BN + wn * (BN / 2) + j * 16 + lm) * 8];
        #pragma unroll
        for (int i = 0; i < RM; i++)
            #pragma unroll
            for (int j = 0; j < RN; j++)
                acc[i][j] = __builtin_amdgcn_mfma_f32_16x16x32_bf16(af[i], bfr[j], acc[i][j], 0, 0, 0);
        __syncthreads();
    }

    const int n_base = nt * BN + wn * (BN / 2);
    const int m_base = mt * BM + wm * (BM / 2);
    int nj[RN]; float bvj[RN];
    #pragma unroll
    for (int j = 0; j < RN; j++) {
        nj[j] = n_base + j * 16 + lm;
        bvj[j] = 0.f;
        if (nj[j] < N && OUT != 4) {
            if (OUT == 0 || OUT == 2 || OUT == 5) bvj[j] = bias[nj[j]];
            else if (blockIdx.z == 0) bvj[j] = bias[nj[j]];
        }
    }
    if constexpr (OUT == 4) {
        float* op = (float*)outv;
        #pragma unroll
        for (int i = 0; i < RM; i++)
            #pragma unroll
            for (int r = 0; r < 4; r++) {
                int m = m_base + i * 16 + quad * 4 + r;
                if (m >= M) continue;
                #pragma unroll
                for (int j = 0; j < RN; j++)
                    if (nj[j] < N) atomicAdd(&op[(size_t)m * N + nj[j]], acc[i][j][r]);
            }
    } else if constexpr (OUT == 5) {
        u16* op = (u16*)outv;
        #pragma unroll
        for (int j = 0; j < RN; j++) {
            if (nj[j] >= N) continue;
            int c = nj[j] / 9, hw = nj[j] - c * 9;
            #pragma unroll
            for (int i = 0; i < RM; i++)
                #pragma unroll
                for (int r = 0; r < 4; r++) {
                    int m = m_base + i * 16 + quad * 4 + r;
                    if (m >= M) continue;
                    op[((size_t)m * 9 + hw) * 1024 + c] = f2bf(acc[i][j][r] + bvj[j]);
                }
        }
    } else if constexpr (OUT == 0 || OUT == 1) {
        int ohw = OH * OW;
        #pragma unroll
        for (int i = 0; i < RM; i++) {
            int m0 = m_base + i * 16 + quad * 4;
            if (m0 >= M) continue;
            int b = m0 / ohw, pix = m0 - b * ohw;  // ohw%4==0, m0%4==0 -> same image
            #pragma unroll
            for (int j = 0; j < RN; j++) {
                if (nj[j] >= N) continue;
                #pragma unroll
                for (int r = 0; r < 4; r++) {
                    float val = acc[i][j][r] + bvj[j];
                    size_t ad = ((size_t)b * ohw + pix + r) * N + nj[j];
                    if (OUT == 0) ((u16*)outv)[ad] = f2bf(val);
                    else atomicAdd(&((float*)outv)[ad], val);
                }
            }
        }
    } else {  // OUT 2/3: ct NHWC
        int OHW = OH * OW, ohwc = OHc * OWc;
        #pragma unroll
        for (int i = 0; i < RM; i++)
            #pragma unroll
            for (int r = 0; r < 4; r++) {
                int m = m_base + i * 16 + quad * 4 + r;
                if (m >= M) continue;
                int b = m / ohwc, rr = m - b * ohwc;
                int oyc = rr / OWc, oxc = rr - (rr / OWc) * OWc;
                size_t ad0 = ((size_t)b * OHW + (2 * oyc + cy) * OW + 2 * oxc + cx) * N;
                #pragma unroll
                for (int j = 0; j < RN; j++) {
                    if (nj[j] >= N) continue;
                    float val = acc[i][j][r] + bvj[j];
                    if (OUT == 2) ((u16*)outv)[ad0 + nj[j]] = f2bf(val);
                    else atomicAdd(&((float*)outv)[ad0 + nj[j]], val);
                }
            }
    }
}

// ===================== weight prep =====================
// conv w [OC][CIN][3][3] fp32 -> bf16 [OC][9*CIN] tap-major
__global__ __launch_bounds__(256)
void convw_prep(const float* __restrict__ src, u16* __restrict__ dst, int lgC, int total) {
    int idx = blockIdx.x * 256 + threadIdx.x;
    if (idx >= total) return;
    int K = 9 << lgC;
    int oc = idx / K, kk = idx - oc * K;
    int tap = kk >> lgC, ic = kk & ((1 << lgC) - 1);
    dst[idx] = f2bf(src[(((size_t)oc << lgC) + ic) * 9 + tap]);
}

// generic transpose + cvt: out[c][r] = bf16(in[r][c]); R,C multiples of 32
__global__ __launch_bounds__(256)
void transpose_cvt(const float* __restrict__ in, u16* __restrict__ out, int R, int C) {
    __shared__ float tl[32][33];
    int c0 = blockIdx.x * 32, r0 = blockIdx.y * 32;
    int tx = threadIdx.x & 31, ty = threadIdx.x >> 5;
    #pragma unroll
    for (int l = 0; l < 4; l++)
        tl[ty + 8 * l][tx] = in[(size_t)(r0 + ty + 8 * l) * C + c0 + tx];
    __syncthreads();
    #pragma unroll
    for (int l = 0; l < 4; l++)
        out[(size_t)(c0 + ty + 8 * l) * R + r0 + tx] = f2bf(tl[tx][ty + 8 * l]);
}

// ct step2: tmp bf16 [OC*9][CIN] -> per-class [OC][T*CIN] (enumeration must match host)
__global__ __launch_bounds__(256)
void ctw_gather(const u16* __restrict__ tmp, u16* __restrict__ outw,
                int CIN, int lgC, int OC, int P) {
    int idx = blockIdx.x * 256 + threadIdx.x;
    if (idx >= (OC << lgC)) return;
    int ic = idx & (CIN - 1);
    int oc = idx >> lgC;
    int off = 0;
    for (int c = 0; c < 4; c++) {
        int cyP = (c >> 1) + P, cxP = (c & 1) + P;
        int nky = ((cyP & 1) == 0) ? 2 : 1;
        int nkx = ((cxP & 1) == 0) ? 2 : 1;
        int T = nky * nkx;
        int ti = 0;
        for (int ky = 0; ky < 3; ky++) {
            if ((cyP + ky) & 1) continue;
            for (int kx = 0; kx < 3; kx++) {
                if ((cxP + kx) & 1) continue;
                outw[off + (size_t)oc * (CIN * T) + ti * CIN + ic] =
                    tmp[((size_t)oc * 9 + ky * 3 + kx) * CIN + ic];
                ti++;
            }
        }
        off += OC * CIN * T;
    }
}

// fc w (16384,800) fp32, k=c*16+hw -> bf16 [n][k'=hw*1024+c]
__global__ __launch_bounds__(256)
void fcw_prep(const float* __restrict__ in, u16* __restrict__ out) {
    __shared__ float tl[32][33];
    int n0 = blockIdx.x * 32, c0 = blockIdx.y * 32, hw = blockIdx.z;
    int tx = threadIdx.x & 31, ty = threadIdx.x >> 5;
    #pragma unroll
    for (int l = 0; l < 4; l++)
        tl[ty + 8 * l][tx] = in[((size_t)(c0 + ty + 8 * l) * 16 + hw) * 800 + n0 + tx];
    __syncthreads();
    #pragma unroll
    for (int l = 0; l < 4; l++)
        out[(size_t)(n0 + ty + 8 * l) * 16384 + hw * 1024 + c0 + tx] = f2bf(tl[tx][ty + 8 * l]);
}

// ct5 weights [64][1][3][3] -> bf16 [9][64]
__global__ __launch_bounds__(256)
void wt5_prep(const float* __restrict__ in, u16* __restrict__ out) {
    int idx = blockIdx.x * 256 + threadIdx.x;
    if (idx >= 576) return;
    int tap = idx >> 6, ic = idx & 63;
    out[idx] = f2bf(in[ic * 9 + tap]);
}

// ===================== non-GEMM =====================
// conv1 (CIN=1) -> bf16 NHWC [b][32*32][128], raw conv + bias
__global__ __launch_bounds__(256)
void conv1_nhwc(const float* __restrict__ x, const float* __restrict__ w,
                const float* __restrict__ bias, u16* __restrict__ out) {
    int idx = blockIdx.x * 256 + threadIdx.x;
    if (idx >= 100 * 1024 * 128) return;
    int oc = idx & 127;
    int pix = (idx >> 7) & 1023;
    int b = idx >> 17;
    int oy = pix >> 5, ox = pix & 31;
    int iy0 = oy * 2 - 1, ix0 = ox * 2 - 1;
    float acc = bias[oc];
    const float* ip = x + (size_t)b * 4096;
    const float* wp = w + oc * 9;
    #pragma unroll
    for (int ky = 0; ky < 3; ky++) {
        int iy = iy0 + ky;
        if ((unsigned)iy >= 64u) continue;
        #pragma unroll
        for (int kx = 0; kx < 3; kx++) {
            int ix = ix0 + kx;
            if ((unsigned)ix >= 64u) continue;
            acc = fmaf(ip[iy * 64 + ix], wp[ky * 3 + kx], acc);
        }
    }
    out[idx] = f2bf(acc);
}

// BN stats over leaky(x): grid MUST be 1024 blocks (stride 262144 % C == 0 for C=128/256/1024)
template<typename T>
__global__ __launch_bounds__(256)
void bnstat(const T* __restrict__ x, float* __restrict__ accum, int C, int total) {
    int idx0 = blockIdx.x * 256 + threadIdx.x;
    int stride = gridDim.x * 256;
    float s = 0.f, q = 0.f;
    for (int i = idx0; i < total; i += stride) {
        float v;
        if constexpr (sizeof(T) == 2) v = bf2f(x[i]); else v = x[i];
        v = v >= 0.f ? v : 0.01f * v;
        s += v; q += v * v;
    }
    int c = idx0 & (C - 1);
    atomicAdd(&accum[c], s);
    atomicAdd(&accum[C + c], q);
}

// BN apply: out bf16 = (leaky(x)-mean)*rsqrt(var+eps)
template<typename T>
__global__ __launch_bounds__(256)
void bnapply(const T* __restrict__ x, u16* __restrict__ out,
             const float* __restrict__ accum, int C, int total, float invcnt) {
    int idx = blockIdx.x * 256 + threadIdx.x;
    if (idx >= total) return;
    int c = idx & (C - 1);
    float mean = accum[c] * invcnt;
    float var = accum[C + c] * invcnt - mean * mean;
    float inv = rsqrtf(var + 1e-5f);
    float v;
    if constexpr (sizeof(T) == 2) v = bf2f(x[idx]); else v = x[idx];
    v = v >= 0.f ? v : 0.01f * v;
    out[idx] = f2bf((v - mean) * inv);
}

__global__ __launch_bounds__(256)
void finalize_relu(const float* __restrict__ acc, const float* __restrict__ bias,
                   float* __restrict__ out) {
    int i = blockIdx.x * 256 + threadIdx.x;
    if (i >= 100 * 800) return;
    float v = acc[i] + bias[i % 800];
    out[i] = fmaxf(v, 0.f);
}

__global__ __launch_bounds__(256)
void dft_real(const float* __restrict__ eig, float* __restrict__ Yr, u16* __restrict__ Yrb) {
    __shared__ float se[800];
    __shared__ float ctab[800];
    int b = blockIdx.x;
    for (int i = threadIdx.x; i < 800; i += 256) {
        se[i] = eig[b * 800 + i];
        ctab[i] = (float)cos(6.283185307179586 * (double)i / 800.0);
    }
    __syncthreads();
    for (int oi = threadIdx.x; oi < 800; oi += 256) {
        int k1 = oi >> 3, k2 = oi & 7;
        int d1 = k1 * 8, d2 = k2 * 100;
        float acc = 0.f;
        int p1 = 0;
        for (int n1 = 0; n1 < 100; n1++) {
            int p = p1;
            #pragma unroll
            for (int n2 = 0; n2 < 8; n2++) {
                acc = fmaf(se[n1 * 8 + n2], ctab[p], acc);
                p += d2; if (p >= 800) p -= 800;
            }
            p1 += d1; if (p1 >= 800) p1 -= 800;
        }
        Yr[b * 800 + oi] = acc;
        Yrb[b * 800 + oi] = f2bf(acc);
    }
}

__global__ __launch_bounds__(256)
void build_C4(const float* __restrict__ Yr, float* __restrict__ C) {
    int idx = blockIdx.x * 256 + threadIdx.x;
    if (idx >= 100 * 800 * 200) return;
    int j4 = (idx % 200) * 4; int tt = idx / 200;
    int i = tt % 800;         int b = tt / 800;
    const float* y = Yr + b * 800;
    f32x4 v;
    #pragma unroll
    for (int r = 0; r < 4; r++) {
        int k = i - (j4 + r);
        k += (k >> 31) & 800;
        v[r] = y[k] * 0.035355339059327376f;
    }
    ((f32x4*)C)[idx] = v;
}

__global__ __launch_bounds__(256)
void cvt_f32bf(const float* __restrict__ in, u16* __restrict__ out, int n) {
    int i = blockIdx.x * 256 + threadIdx.x;
    if (i < n) out[i] = f2bf(in[i]);
}

// ct5: stride-1 convT, OC=1, NHWC bf16 input [b][47*47][64]
__global__ __launch_bounds__(256)
void convT5(const u16* __restrict__ in, const u16* __restrict__ w,
            const float* __restrict__ bias, float* __restrict__ out) {
    int idx = blockIdx.x * 256 + threadIdx.x;
    if (idx >= 100 * 49 * 49) return;
    int ox = idx % 49; int t2 = idx / 49;
    int oy = t2 % 49;  int b = t2 / 49;
    float acc = bias[0];
    for (int ky = 0; ky < 3; ky++) {
        int iy = oy - ky;
        if ((unsigned)iy >= 47u) continue;
        for (int kx = 0; kx < 3; kx++) {
            int ix = ox - kx;
            if ((unsigned)ix >= 47u) continue;
            const uint4* ip = (const uint4*)(in + (((size_t)b * 47 + iy) * 47 + ix) * 64);
            const uint4* wp = (const uint4*)(w + (ky * 3 + kx) * 64);
            #pragma unroll
            for (int g = 0; g < 8; g++) {
                uint4 av = ip[g], wv = wp[g];
                const unsigned* aa = (const unsigned*)&av;
                const unsigned* ww = (const unsigned*)&wv;
                #pragma unroll
                for (int h = 0; h < 4; h++) {
                    float a0 = __builtin_bit_cast(float, aa[h] << 16);
                    float a1 = __builtin_bit_cast(float, aa[h] & 0xFFFF0000u);
                    float w0 = __builtin_bit_cast(float, ww[h] << 16);
                    float w1 = __builtin_bit_cast(float, ww[h] & 0xFFFF0000u);
                    acc = fmaf(a0, w0, acc);
                    acc = fmaf(a1, w1, acc);
                }
            }
        }
    }
    out[idx] = acc;
}

// ===================== host helpers =====================
struct CTClass { int T, OHc, OWc, dyp, dxp, off, K; };
static void ct_params(int P, int OH, int OW, int CIN, int OC, CTClass cls[4]) {
    int off = 0;
    for (int c = 0; c < 4; c++) {
        int cy = c >> 1, cx = c & 1;
        int kys[2], dys[2], nky = 0, kxs[2], dxs[2], nkx = 0;
        for (int ky = 0; ky < 3; ky++)
            if (((cy + P + ky) & 1) == 0) { kys[nky] = ky; dys[nky] = (cy + P - ky) / 2; nky++; }
        for (int kx = 0; kx < 3; kx++)
            if (((cx + P + kx) & 1) == 0) { kxs[nkx] = kx; dxs[nkx] = (cx + P - kx) / 2; nkx++; }
        CTClass& cc = cls[c];
        cc.T = nky * nkx;
        cc.OHc = (OH - cy + 1) >> 1; cc.OWc = (OW - cx + 1) >> 1;
        cc.dyp = 0; cc.dxp = 0;
        int ti = 0;
        for (int a = 0; a < nky; a++)
            for (int b2 = 0; b2 < nkx; b2++, ti++) {
                cc.dyp |= (dys[a] & 255) << (8 * ti);
                cc.dxp |= (dxs[b2] & 255) << (8 * ti);
            }
        cc.off = off; cc.K = CIN * cc.T;
        off += OC * cc.K;
    }
}

template<int BM, int OUTK>
static void launch_ct(hipStream_t s, const u16* in, const u16* W, const float* bias, void* outp,
                      int lgC, int OC, int IH, int IW, int OH, int OW,
                      const CTClass* cls, const int* zs) {
    for (int c = 0; c < 4; c++) {
        const CTClass& cc = cls[c];
        int M = 100 * cc.OHc * cc.OWc;
        int z = zs[c];
        dim3 g((M + BM - 1) / BM, (OC + 63) / 64, z);
        gemm<2, OUTK, BM, 64><<<g, 256, 0, s>>>(
            in, W + cc.off, bias, outp, M, OC, cc.K, lgC,
            IH, IW, OH, OW, cc.OHc, cc.OWc, c >> 1, c & 1, cc.dyp, cc.dxp, cc.K / z);
    }
}

extern "C" void kernel_launch(void* const* d_in, const int* in_sizes, int n_in,
                              void* d_out, int out_size, void* d_ws, size_t ws_size,
                              hipStream_t stream) {
    const float* x    = (const float*)d_in[0];
    const float* c1w  = (const float*)d_in[1];  const float* c1b = (const float*)d_in[2];
    const float* c2w  = (const float*)d_in[3];  const float* c2b = (const float*)d_in[4];
    const float* c3w  = (const float*)d_in[5];  const float* c3b = (const float*)d_in[6];
    const float* c4w  = (const float*)d_in[7];  const float* c4b = (const float*)d_in[8];
    const float* fcw  = (const float*)d_in[9];  const float* fcb = (const float*)d_in[10];
    const float* decw = (const float*)d_in[11]; const float* decb = (const float*)d_in[12];
    const float* t1w  = (const float*)d_in[13]; const float* t1b = (const float*)d_in[14];
    const float* t2w  = (const float*)d_in[15]; const float* t2b = (const float*)d_in[16];
    const float* t3w  = (const float*)d_in[17]; const float* t3b = (const float*)d_in[18];
    const float* t4w  = (const float*)d_in[19]; const float* t4b = (const float*)d_in[20];
    const float* t5w  = (const float*)d_in[21]; const float* t5b = (const float*)d_in[22];

    float* out = (float*)d_out;
    float* d_final = out;
    float* Cmat    = out + 240100;
    float* eig     = out + 240100 + 64000000;

    float* ws = (float*)d_ws;
    // ---- workspace layout (float units), budget 27,244,800 ----
    u16*   h1    = (u16*)(ws);                 // 13,107,200 bf16 (6,553,600 f) [conv1->conv2]
    u16*   W_fc  = (u16*)(ws);                 // 13,107,200 bf16 @0 (after conv2 done)
    u16*   h2    = (u16*)(ws + 6553600);       // 6,553,600 bf16
    u16*   h3    = (u16*)(ws + 9830400);       // 6,553,600 bf16
    u16*   W_c2  = (u16*)(ws + 13107200);      // 294,912 bf16
    u16*   W_c3  = (u16*)(ws + 13254656);      // 2,359,296 bf16
    u16*   W_c4  = (u16*)(ws + 14434304);      // 9,437,184 bf16
    float* h4f   = ws + 19152896;              // 1,638,400 f32
    u16*   h4    = (u16*)(ws + 20791296);      // 1,638,400 bf16
    float* accum = ws + 21610496;              // 2,048 f32
    float* facc  = ws + 21612544;              // 80,000 f32
    float* Yr    = ws + 21692544;              // 80,000 f32
    u16*   Yrb   = (u16*)(ws + 21772544);      // 80,000 bf16
    u16*   d0    = (u16*)(ws + 21812544);      // 921,600 bf16
    u16*   W_dec = (u16*)(ws + 22273344);      // 7,372,800 bf16  -> ends 25,959,744
    // decoder phase (encoder region reused)
    u16*   W_t1  = (u16*)(ws);                 // 4,718,592 bf16
    u16*   W_t2  = (u16*)(ws);                 // after ct1
    u16*   W_t3  = (u16*)(ws);                 // after ct2
    u16*   W_t4  = (u16*)(ws);                 // after ct3
    u16*   W_t5  = (u16*)(ws + 100000);
    u16*   tmpw  = (u16*)(ws + 2359296);       // up to 4,718,592 bf16
    float* o1f   = ws + 4718592;               // 1,280,000 f32
    u16*   o1    = (u16*)(ws + 5998592);       // 1,280,000 bf16
    float* o2f   = ws + 6638592;               // 3,097,600 f32
    u16*   o2    = (u16*)(ws + 9736192);       // 3,097,600 bf16
    u16*   o3    = (u16*)(ws + 11284992);      // 6,771,200 bf16
    u16*   o4    = (u16*)(ws + 14670592);      // 14,137,600 bf16 -> ends 21,739,392

    #define GRID(n) dim3(((n) + 255) / 256)

    // ======== encoder ========
    conv1_nhwc<<<GRID(13107200), 256, 0, stream>>>(x, c1w, c1b, h1);
    hipMemsetAsync(accum, 0, 2048 * 4, stream);
    bnstat<u16><<<1024, 256, 0, stream>>>(h1, accum, 128, 13107200);
    bnapply<u16><<<GRID(13107200), 256, 0, stream>>>(h1, h1, accum, 128, 13107200, 1.f / 102400.f);

    convw_prep<<<GRID(294912), 256, 0, stream>>>(c2w, W_c2, 7, 294912);
    gemm<1, 0, 128, 64><<<dim3(200, 4, 1), 256, 0, stream>>>(
        h1, W_c2, c2b, h2, 25600, 256, 1152, 7, 32, 32, 16, 16, 0, 0, 0, 0, 0, 0, 1152);
    hipMemsetAsync(accum, 0, 2048 * 4, stream);
    bnstat<u16><<<1024, 256, 0, stream>>>(h2, accum, 256, 6553600);
    bnapply<u16><<<GRID(6553600), 256, 0, stream>>>(h2, h2, accum, 256, 6553600, 1.f / 25600.f);

    convw_prep<<<GRID(2359296), 256, 0, stream>>>(c3w, W_c3, 8, 2359296);
    gemm<1, 0, 128, 128><<<dim3(50, 8, 1), 256, 0, stream>>>(
        h2, W_c3, c3b, h3, 6400, 1024, 2304, 8, 16, 16, 8, 8, 0, 0, 0, 0, 0, 0, 2304);
    hipMemsetAsync(accum, 0, 2048 * 4, stream);
    bnstat<u16><<<1024, 256, 0, stream>>>(h3, accum, 1024, 6553600);
    bnapply<u16><<<GRID(6553600), 256, 0, stream>>>(h3, h3, accum, 1024, 6553600, 1.f / 6400.f);

    convw_prep<<<GRID(9437184), 256, 0, stream>>>(c4w, W_c4, 10, 9437184);
    hipMemsetAsync(h4f, 0, 1638400 * 4, stream);
    gemm<1, 1, 64, 128><<<dim3(25, 8, 2), 256, 0, stream>>>(
        h3, W_c4, c4b, h4f, 1600, 1024, 9216, 10, 8, 8, 4, 4, 0, 0, 0, 0, 0, 0, 4608);
    hipMemsetAsync(accum, 0, 2048 * 4, stream);
    bnstat<float><<<1024, 256, 0, stream>>>(h4f, accum, 1024, 1638400);
    bnapply<float><<<GRID(1638400), 256, 0, stream>>>(h4f, h4, accum, 1024, 1638400, 1.f / 1600.f);

    // ======== fc (split-K z=16) ========
    fcw_prep<<<dim3(25, 32, 16), 256, 0, stream>>>(fcw, W_fc);
    hipMemsetAsync(facc, 0, 80000 * 4, stream);
    gemm<0, 4, 64, 64><<<dim3(2, 13, 16), 256, 0, stream>>>(
        h4, W_fc, nullptr, facc, 100, 800, 16384, 0, 0, 0, 0, 0, 0, 0, 0, 0, 0, 0, 1024);
    finalize_relu<<<GRID(80000), 256, 0, stream>>>(facc, fcb, eig);

    // ======== FFT block ========
    dft_real<<<dim3(100), 256, 0, stream>>>(eig, Yr, Yrb);
    build_C4<<<GRID(16000000), 256, 0, stream>>>(Yr, Cmat);

    // ======== dec matmul (epilogue permutes to NHWC d0) ========
    transpose_cvt<<<dim3(288, 25), 256, 0, stream>>>(decw, W_dec, 800, 9216);
    gemm<0, 5, 64, 64><<<dim3(2, 144, 1), 256, 0, stream>>>(
        Yrb, W_dec, decb, d0, 100, 9216, 800, 0, 0, 0, 0, 0, 0, 0, 0, 0, 0, 0, 800);

    // ======== decoder convT stack (parity classes) ========
    CTClass c1c[4], c2c[4], c3c[4], c4c[4];
    ct_params(1, 5, 5, 1024, 512, c1c);
    ct_params(0, 11, 11, 512, 256, c2c);
    ct_params(0, 23, 23, 256, 128, c3c);
    ct_params(0, 47, 47, 128, 64, c4c);

    static const int zs1[4] = {2, 2, 2, 4};
    static const int zs2[4] = {2, 2, 2, 1};
    static const int zs3[4] = {1, 1, 1, 1};
    static const int zs4[4] = {1, 1, 1, 1};

    transpose_cvt<<<dim3(144, 32), 256, 0, stream>>>(t1w, tmpw, 1024, 4608);
    ctw_gather<<<GRID(524288), 256, 0, stream>>>(tmpw, W_t1, 1024, 10, 512, 1);
    hipMemsetAsync(o1f, 0, 1280000 * 4, stream);
    launch_ct<64, 3>(stream, d0, W_t1, t1b, o1f, 10, 512, 3, 3, 5, 5, c1c, zs1);
    cvt_f32bf<<<GRID(1280000), 256, 0, stream>>>(o1f, o1, 1280000);

    transpose_cvt<<<dim3(72, 16), 256, 0, stream>>>(t2w, tmpw, 512, 2304);
    ctw_gather<<<GRID(131072), 256, 0, stream>>>(tmpw, W_t2, 512, 9, 256, 0);
    hipMemsetAsync(o2f, 0, 3097600 * 4, stream);
    launch_ct<64, 3>(stream, o1, W_t2, t2b, o2f, 9, 256, 5, 5, 11, 11, c2c, zs2);
    cvt_f32bf<<<GRID(3097600), 256, 0, stream>>>(o2f, o2, 3097600);

    transpose_cvt<<<dim3(36, 8), 256, 0, stream>>>(t3w, tmpw, 256, 1152);
    ctw_gather<<<GRID(32768), 256, 0, stream>>>(tmpw, W_t3, 256, 8, 128, 0);
    launch_ct<64, 2>(stream, o2, W_t3, t3b, o3, 8, 128, 11, 11, 23, 23, c3c, zs3);

    transpose_cvt<<<dim3(18, 4), 256, 0, stream>>>(t4w, tmpw, 128, 576);
    ctw_gather<<<GRID(8192), 256, 0, stream>>>(tmpw, W_t4, 128, 7, 64, 0);
    launch_ct<128, 2>(stream, o3, W_t4, t4b, o4, 7, 64, 23, 23, 47, 47, c4c, zs4);

    wt5_prep<<<GRID(576), 256, 0, stream>>>(t5w, W_t5);
    convT5<<<GRID(240100), 256, 0, stream>>>(o4, W_t5, t5b, d_final);

    #undef GRID
}

// Round 6
// 1295.608 us; speedup vs baseline: 46.1495x; 1.1391x over previous
//
#include <hip/hip_runtime.h>
#include <math.h>

typedef __attribute__((ext_vector_type(8))) short bf16x8;
typedef __attribute__((ext_vector_type(4))) float f32x4;
typedef unsigned short u16;

__device__ __forceinline__ u16 f2bf(float f) {
    unsigned u = __builtin_bit_cast(unsigned, f);
    u += 0x7FFFu + ((u >> 16) & 1u);   // RNE
    return (u16)(u >> 16);
}
__device__ __forceinline__ float bf2f(u16 h) {
    unsigned u = ((unsigned)h) << 16;
    return __builtin_bit_cast(float, u);
}

// =====================================================================
// MFMA GEMM.
// MODE 0: A = bf16 [M][K] rows            (fc, dec)
// MODE 1: A = im2col of bf16 NHWC input, conv3x3 s2 p1; k = tap*CIN+ic
// OUT  0: bf16 NHWC conv (+bias; optional fused BN stats)
// OUT  1: fp32 atomic NHWC conv (+bias at z==0)
// OUT  4: fp32 atomic plain (no bias)
// OUT  5: bf16 dec-permuted [m][hw][c] (+bias)
// SWIZ 1: 1D grid, nt = id&7 (requires N/BN == 8) -> per-XCD weight L2 reuse
// =====================================================================
template<int MODE, int OUT, int BM, int BN, int SWIZ, bool STATS>
__global__ __launch_bounds__(256, 3)
void gemm(const u16* __restrict__ Abf, const u16* __restrict__ Bw,
          const float* __restrict__ bias, void* __restrict__ outv,
          float* __restrict__ stat,
          int M, int N, int K, int lgC,
          int IH, int IW, int OH, int OW, int zchunk)
{
    constexpr int ANSEG = BM / 64, BNSEG = BN / 64;
    constexpr int RM = BM / 32, RN = BN / 32;
    __shared__ __align__(16) u16 As[4 * BM * 8];
    __shared__ __align__(16) u16 Bs[4 * BN * 8];
    const int t = threadIdx.x;
    const int lane = t & 63, wave = t >> 6;
    const int lm = lane & 15, quad = lane >> 4;
    const int wm = wave & 1, wn = wave >> 1;
    int mt, nt, z;
    if (SWIZ == 1) {
        int mtN = (M + BM - 1) / BM;
        int id = blockIdx.x;
        nt = id & 7; int j = id >> 3;
        mt = j % mtN; z = j / mtN;
    } else { mt = blockIdx.x; nt = blockIdx.y; z = blockIdx.z; }
    const int k0 = z * zchunk, kend = k0 + zchunk;

    const int arow = (ANSEG == 2) ? (t >> 1) : (t >> 2);
    const int akb  = (ANSEG == 2) ? (t & 1) * 16 : (t & 3) * 8;
    const int a_gm = mt * BM + arow;
    const bool a_in = a_gm < M;
    int oy = 0, ox = 0, bimg = 0;
    if (MODE == 1) {
        int ohw = OH * OW;
        int g = a_in ? a_gm : 0;
        bimg = g / ohw; int r = g - bimg * ohw;
        oy = r / OW; ox = r - (r / OW) * OW;
    }
    const int brow = (BNSEG == 2) ? (t >> 1) : (t >> 2);
    const int bkb  = (BNSEG == 2) ? (t & 1) * 16 : (t & 3) * 8;
    const int b_gn = nt * BN + brow;
    const bool b_in = b_gn < N;

    f32x4 acc[RM][RN];
    #pragma unroll
    for (int i = 0; i < RM; i++)
        #pragma unroll
        for (int j = 0; j < RN; j++) acc[i][j] = (f32x4){0.f, 0.f, 0.f, 0.f};

    for (int kb = k0; kb < kend; kb += 32) {
        #pragma unroll
        for (int s = 0; s < ANSEG; s++) {
            int kk = kb + akb + s * 8;
            uint4 v = make_uint4(0, 0, 0, 0);
            if (MODE == 0) {
                if (a_in) v = *(const uint4*)(Abf + (size_t)a_gm * K + kk);
            } else {
                int tap = kk >> lgC;
                int ic = kk & ((1 << lgC) - 1);
                int ky = tap / 3, kx = tap - (tap / 3) * 3;
                int iy = oy * 2 - 1 + ky, ix = ox * 2 - 1 + kx;
                if (a_in && (unsigned)iy < (unsigned)IH && (unsigned)ix < (unsigned)IW)
                    v = *(const uint4*)(Abf + ((((size_t)bimg * IH + iy) * IW + ix) << lgC) + ic);
            }
            *(uint4*)&As[(((akb >> 3) + s) * BM + arow) * 8] = v;
        }
        #pragma unroll
        for (int s = 0; s < BNSEG; s++) {
            int kk = kb + bkb + s * 8;
            uint4 v = make_uint4(0, 0, 0, 0);
            if (b_in) v = *(const uint4*)(Bw + (size_t)b_gn * K + kk);
            *(uint4*)&Bs[(((bkb >> 3) + s) * BN + brow) * 8] = v;
        }
        __syncthreads();
        bf16x8 af[RM], bfr[RN];
        #pragma unroll
        for (int i = 0; i < RM; i++)
            af[i] = *(const bf16x8*)&As[(size_t)(quad * BM + wm * (BM / 2) + i * 16 + lm) * 8];
        #pragma unroll
        for (int j = 0; j < RN; j++)
            bfr[j] = *(const bf16x8*)&Bs[(size_t)(quad * BN + wn * (BN / 2) + j * 16 + lm) * 8];
        #pragma unroll
        for (int i = 0; i < RM; i++)
            #pragma unroll
            for (int j = 0; j < RN; j++)
                acc[i][j] = __builtin_amdgcn_mfma_f32_16x16x32_bf16(af[i], bfr[j], acc[i][j], 0, 0, 0);
        __syncthreads();
    }

    const int n_base = nt * BN + wn * (BN / 2);
    const int m_base = mt * BM + wm * (BM / 2);
    int nj[RN]; float bvj[RN];
    #pragma unroll
    for (int j = 0; j < RN; j++) {
        nj[j] = n_base + j * 16 + lm;
        bvj[j] = 0.f;
        if (nj[j] < N && OUT != 4) {
            if (OUT == 0 || OUT == 5) bvj[j] = bias[nj[j]];
            else if (z == 0) bvj[j] = bias[nj[j]];
        }
    }
    if constexpr (OUT == 4) {
        float* op = (float*)outv;
        #pragma unroll
        for (int i = 0; i < RM; i++)
            #pragma unroll
            for (int r = 0; r < 4; r++) {
                int m = m_base + i * 16 + quad * 4 + r;
                if (m >= M) continue;
                #pragma unroll
                for (int j = 0; j < RN; j++)
                    if (nj[j] < N) atomicAdd(&op[(size_t)m * N + nj[j]], acc[i][j][r]);
            }
    } else if constexpr (OUT == 5) {
        u16* op = (u16*)outv;
        #pragma unroll
        for (int j = 0; j < RN; j++) {
            if (nj[j] >= N) continue;
            int c = nj[j] / 9, hw = nj[j] - c * 9;
            #pragma unroll
            for (int i = 0; i < RM; i++)
                #pragma unroll
                for (int r = 0; r < 4; r++) {
                    int m = m_base + i * 16 + quad * 4 + r;
                    if (m >= M) continue;
                    op[((size_t)m * 9 + hw) * 1024 + c] = f2bf(acc[i][j][r] + bvj[j]);
                }
        }
    } else if constexpr (OUT == 0) {
        int ohw = OH * OW;
        float sj[RN], qj[RN];
        #pragma unroll
        for (int j = 0; j < RN; j++) { sj[j] = 0.f; qj[j] = 0.f; }
        #pragma unroll
        for (int i = 0; i < RM; i++) {
            int m0 = m_base + i * 16 + quad * 4;
            if (m0 >= M) continue;
            int b = m0 / ohw, pix = m0 - b * ohw;  // ohw%4==0, m0%4==0 -> same image
            #pragma unroll
            for (int j = 0; j < RN; j++) {
                if (nj[j] >= N) continue;
                #pragma unroll
                for (int r = 0; r < 4; r++) {
                    float val = acc[i][j][r] + bvj[j];
                    ((u16*)outv)[((size_t)b * ohw + pix + r) * N + nj[j]] = f2bf(val);
                    if (STATS) {
                        float lv = val >= 0.f ? val : 0.01f * val;
                        sj[j] += lv; qj[j] += lv * lv;
                    }
                }
            }
        }
        if constexpr (STATS) {
            #pragma unroll
            for (int j = 0; j < RN; j++) {
                float s = sj[j], q = qj[j];
                s += __shfl_down(s, 32); q += __shfl_down(q, 32);
                s += __shfl_down(s, 16); q += __shfl_down(q, 16);
                if (quad == 0 && nj[j] < N) {
                    atomicAdd(&stat[nj[j]], s);
                    atomicAdd(&stat[N + nj[j]], q);
                }
            }
        }
    } else {  // OUT 1
        int ohw = OH * OW;
        #pragma unroll
        for (int i = 0; i < RM; i++) {
            int m0 = m_base + i * 16 + quad * 4;
            if (m0 >= M) continue;
            int b = m0 / ohw, pix = m0 - b * ohw;
            #pragma unroll
            for (int j = 0; j < RN; j++) {
                if (nj[j] >= N) continue;
                #pragma unroll
                for (int r = 0; r < 4; r++)
                    atomicAdd(&((float*)outv)[((size_t)b * ohw + pix + r) * N + nj[j]],
                              acc[i][j][r] + bvj[j]);
            }
        }
    }
}

// =========== all-class convT GEMM: grid.z = parity class ===========
template<int BM>
__global__ __launch_bounds__(256, 3)
void gemm_ct(const u16* __restrict__ Abf, const u16* __restrict__ Wb,
             const float* __restrict__ bias, u16* __restrict__ out,
             int N, int lgC, int IH, int IW, int OH, int OW,
             int4 Kc, int4 Mc, int4 Hc, int4 Wc, int4 Oc, int4 Dy, int4 Dx)
{
    constexpr int ANSEG = BM / 64;
    constexpr int RM = BM / 32, RN = 2;
    const int c = blockIdx.z;
    const int Ks[4] = {Kc.x, Kc.y, Kc.z, Kc.w};
    const int Ms[4] = {Mc.x, Mc.y, Mc.z, Mc.w};
    const int Hs[4] = {Hc.x, Hc.y, Hc.z, Hc.w};
    const int Wsz[4]= {Wc.x, Wc.y, Wc.z, Wc.w};
    const int Os[4] = {Oc.x, Oc.y, Oc.z, Oc.w};
    const int Dys[4]= {Dy.x, Dy.y, Dy.z, Dy.w};
    const int Dxs[4]= {Dx.x, Dx.y, Dx.z, Dx.w};
    const int K = Ks[c], M = Ms[c], OHc = Hs[c], OWc = Wsz[c];
    const int dyp = Dys[c], dxp = Dxs[c];
    const int mt = blockIdx.x, nt = blockIdx.y;
    if (mt * BM >= M) return;
    const u16* Bw = Wb + Os[c];

    __shared__ __align__(16) u16 As[4 * BM * 8];
    __shared__ __align__(16) u16 Bs[4 * 64 * 8];
    const int t = threadIdx.x;
    const int lane = t & 63, wave = t >> 6;
    const int lm = lane & 15, quad = lane >> 4;
    const int wm = wave & 1, wn = wave >> 1;

    const int arow = (ANSEG == 2) ? (t >> 1) : (t >> 2);
    const int akb  = (ANSEG == 2) ? (t & 1) * 16 : (t & 3) * 8;
    const int a_gm = mt * BM + arow;
    const bool a_in = a_gm < M;
    const int ohwc = OHc * OWc;
    int g = a_in ? a_gm : 0;
    int bimg = g / ohwc; int rr = g - bimg * ohwc;
    int oy = rr / OWc, ox = rr - (rr / OWc) * OWc;

    const int brow = t >> 2;
    const int bkb  = (t & 3) * 8;
    const int b_gn = nt * 64 + brow;
    const bool b_in = b_gn < N;

    f32x4 acc[RM][RN];
    #pragma unroll
    for (int i = 0; i < RM; i++)
        #pragma unroll
        for (int j = 0; j < RN; j++) acc[i][j] = (f32x4){0.f, 0.f, 0.f, 0.f};

    for (int kb = 0; kb < K; kb += 32) {
        #pragma unroll
        for (int s = 0; s < ANSEG; s++) {
            int kk = kb + akb + s * 8;
            uint4 v = make_uint4(0, 0, 0, 0);
            int ti = kk >> lgC;
            int ic = kk & ((1 << lgC) - 1);
            int dy = (int)(signed char)((dyp >> (8 * ti)) & 255);
            int dx = (int)(signed char)((dxp >> (8 * ti)) & 255);
            int iy = oy + dy, ix = ox + dx;
            if (a_in && (unsigned)iy < (unsigned)IH && (unsigned)ix < (unsigned)IW)
                v = *(const uint4*)(Abf + ((((size_t)bimg * IH + iy) * IW + ix) << lgC) + ic);
            *(uint4*)&As[(((akb >> 3) + s) * BM + arow) * 8] = v;
        }
        {
            uint4 v = make_uint4(0, 0, 0, 0);
            if (b_in) v = *(const uint4*)(Bw + (size_t)b_gn * K + kb + bkb);
            *(uint4*)&Bs[((bkb >> 3) * 64 + brow) * 8] = v;
        }
        __syncthreads();
        bf16x8 af[RM], bfr[RN];
        #pragma unroll
        for (int i = 0; i < RM; i++)
            af[i] = *(const bf16x8*)&As[(size_t)(quad * BM + wm * (BM / 2) + i * 16 + lm) * 8];
        #pragma unroll
        for (int j = 0; j < RN; j++)
            bfr[j] = *(const bf16x8*)&Bs[(size_t)(quad * 64 + wn * 32 + j * 16 + lm) * 8];
        #pragma unroll
        for (int i = 0; i < RM; i++)
            #pragma unroll
            for (int j = 0; j < RN; j++)
                acc[i][j] = __builtin_amdgcn_mfma_f32_16x16x32_bf16(af[i], bfr[j], acc[i][j], 0, 0, 0);
        __syncthreads();
    }

    const int n_base = nt * 64 + wn * 32;
    const int m_base = mt * BM + wm * (BM / 2);
    const int cy = c >> 1, cx = c & 1;
    const int OHW = OH * OW;
    int nj[RN]; float bvj[RN];
    #pragma unroll
    for (int j = 0; j < RN; j++) {
        nj[j] = n_base + j * 16 + lm;
        bvj[j] = (nj[j] < N) ? bias[nj[j]] : 0.f;
    }
    #pragma unroll
    for (int i = 0; i < RM; i++)
        #pragma unroll
        for (int r = 0; r < 4; r++) {
            int m = m_base + i * 16 + quad * 4 + r;
            if (m >= M) continue;
            int b = m / ohwc, r2 = m - b * ohwc;
            int oyc = r2 / OWc, oxc = r2 - (r2 / OWc) * OWc;
            size_t ad0 = ((size_t)b * OHW + (2 * oyc + cy) * OW + 2 * oxc + cx) * N;
            #pragma unroll
            for (int j = 0; j < RN; j++)
                if (nj[j] < N) out[ad0 + nj[j]] = f2bf(acc[i][j][r] + bvj[j]);
        }
}

// ===================== weight prep =====================
__global__ __launch_bounds__(256)
void convw_prep(const float* __restrict__ src, u16* __restrict__ dst, int lgC, int total) {
    int idx = blockIdx.x * 256 + threadIdx.x;
    if (idx >= total) return;
    int K = 9 << lgC;
    int oc = idx / K, kk = idx - oc * K;
    int tap = kk >> lgC, ic = kk & ((1 << lgC) - 1);
    dst[idx] = f2bf(src[(((size_t)oc << lgC) + ic) * 9 + tap]);
}

__global__ __launch_bounds__(256)
void transpose_cvt(const float* __restrict__ in, u16* __restrict__ out, int R, int C) {
    __shared__ float tl[32][33];
    int c0 = blockIdx.x * 32, r0 = blockIdx.y * 32;
    int tx = threadIdx.x & 31, ty = threadIdx.x >> 5;
    #pragma unroll
    for (int l = 0; l < 4; l++)
        tl[ty + 8 * l][tx] = in[(size_t)(r0 + ty + 8 * l) * C + c0 + tx];
    __syncthreads();
    #pragma unroll
    for (int l = 0; l < 4; l++)
        out[(size_t)(c0 + ty + 8 * l) * R + r0 + tx] = f2bf(tl[tx][ty + 8 * l]);
}

__global__ __launch_bounds__(256)
void ctw_gather(const u16* __restrict__ tmp, u16* __restrict__ outw,
                int CIN, int lgC, int OC, int P) {
    int idx = blockIdx.x * 256 + threadIdx.x;
    if (idx >= (OC << lgC)) return;
    int ic = idx & (CIN - 1);
    int oc = idx >> lgC;
    int off = 0;
    for (int c = 0; c < 4; c++) {
        int cyP = (c >> 1) + P, cxP = (c & 1) + P;
        int nky = ((cyP & 1) == 0) ? 2 : 1;
        int nkx = ((cxP & 1) == 0) ? 2 : 1;
        int T = nky * nkx;
        int ti = 0;
        for (int ky = 0; ky < 3; ky++) {
            if ((cyP + ky) & 1) continue;
            for (int kx = 0; kx < 3; kx++) {
                if ((cxP + kx) & 1) continue;
                outw[off + (size_t)oc * (CIN * T) + ti * CIN + ic] =
                    tmp[((size_t)oc * 9 + ky * 3 + kx) * CIN + ic];
                ti++;
            }
        }
        off += OC * CIN * T;
    }
}

__global__ __launch_bounds__(256)
void fcw_prep(const float* __restrict__ in, u16* __restrict__ out) {
    __shared__ float tl[32][33];
    int n0 = blockIdx.x * 32, c0 = blockIdx.y * 32, hw = blockIdx.z;
    int tx = threadIdx.x & 31, ty = threadIdx.x >> 5;
    #pragma unroll
    for (int l = 0; l < 4; l++)
        tl[ty + 8 * l][tx] = in[((size_t)(c0 + ty + 8 * l) * 16 + hw) * 800 + n0 + tx];
    __syncthreads();
    #pragma unroll
    for (int l = 0; l < 4; l++)
        out[(size_t)(n0 + ty + 8 * l) * 16384 + hw * 1024 + c0 + tx] = f2bf(tl[tx][ty + 8 * l]);
}

__global__ __launch_bounds__(256)
void wt5_prep(const float* __restrict__ in, u16* __restrict__ out) {
    int idx = blockIdx.x * 256 + threadIdx.x;
    if (idx >= 576) return;
    int tap = idx >> 6, ic = idx & 63;
    out[idx] = f2bf(in[ic * 9 + tap]);
}

// ===================== non-GEMM =====================
__global__ __launch_bounds__(256)
void conv1_nhwc(const float* __restrict__ x, const float* __restrict__ w,
                const float* __restrict__ bias, u16* __restrict__ out) {
    int idx = blockIdx.x * 256 + threadIdx.x;
    if (idx >= 100 * 1024 * 128) return;
    int oc = idx & 127;
    int pix = (idx >> 7) & 1023;
    int b = idx >> 17;
    int oy = pix >> 5, ox = pix & 31;
    int iy0 = oy * 2 - 1, ix0 = ox * 2 - 1;
    float acc = bias[oc];
    const float* ip = x + (size_t)b * 4096;
    const float* wp = w + oc * 9;
    #pragma unroll
    for (int ky = 0; ky < 3; ky++) {
        int iy = iy0 + ky;
        if ((unsigned)iy >= 64u) continue;
        #pragma unroll
        for (int kx = 0; kx < 3; kx++) {
            int ix = ix0 + kx;
            if ((unsigned)ix >= 64u) continue;
            acc = fmaf(ip[iy * 64 + ix], wp[ky * 3 + kx], acc);
        }
    }
    out[idx] = f2bf(acc);
}

template<typename T>
__global__ __launch_bounds__(256)
void bnstat(const T* __restrict__ x, float* __restrict__ accum, int C, int total) {
    int idx0 = blockIdx.x * 256 + threadIdx.x;
    int stride = gridDim.x * 256;
    float s = 0.f, q = 0.f;
    for (int i = idx0; i < total; i += stride) {
        float v;
        if constexpr (sizeof(T) == 2) v = bf2f(x[i]); else v = x[i];
        v = v >= 0.f ? v : 0.01f * v;
        s += v; q += v * v;
    }
    int c = idx0 & (C - 1);
    atomicAdd(&accum[c], s);
    atomicAdd(&accum[C + c], q);
}

template<typename T>
__global__ __launch_bounds__(256)
void bnapply(const T* __restrict__ x, u16* __restrict__ out,
             const float* __restrict__ accum, int C, int total, float invcnt) {
    int idx = blockIdx.x * 256 + threadIdx.x;
    if (idx >= total) return;
    int c = idx & (C - 1);
    float mean = accum[c] * invcnt;
    float var = accum[C + c] * invcnt - mean * mean;
    float inv = rsqrtf(var + 1e-5f);
    float v;
    if constexpr (sizeof(T) == 2) v = bf2f(x[idx]); else v = x[idx];
    v = v >= 0.f ? v : 0.01f * v;
    out[idx] = f2bf((v - mean) * inv);
}

__global__ __launch_bounds__(256)
void finalize_relu(const float* __restrict__ acc, const float* __restrict__ bias,
                   float* __restrict__ out) {
    int i = blockIdx.x * 256 + threadIdx.x;
    if (i >= 100 * 800) return;
    float v = acc[i] + bias[i % 800];
    out[i] = fmaxf(v, 0.f);
}

__global__ __launch_bounds__(256)
void dft_real(const float* __restrict__ eig, float* __restrict__ Yr, u16* __restrict__ Yrb) {
    __shared__ float se[800];
    __shared__ float ctab[800];
    int b = blockIdx.x;
    for (int i = threadIdx.x; i < 800; i += 256) {
        se[i] = eig[b * 800 + i];
        ctab[i] = (float)cos(6.283185307179586 * (double)i / 800.0);
    }
    __syncthreads();
    for (int oi = threadIdx.x; oi < 800; oi += 256) {
        int k1 = oi >> 3, k2 = oi & 7;
        int d1 = k1 * 8, d2 = k2 * 100;
        float acc = 0.f;
        int p1 = 0;
        for (int n1 = 0; n1 < 100; n1++) {
            int p = p1;
            #pragma unroll
            for (int n2 = 0; n2 < 8; n2++) {
                acc = fmaf(se[n1 * 8 + n2], ctab[p], acc);
                p += d2; if (p >= 800) p -= 800;
            }
            p1 += d1; if (p1 >= 800) p1 -= 800;
        }
        Yr[b * 800 + oi] = acc;
        Yrb[b * 800 + oi] = f2bf(acc);
    }
}

__global__ __launch_bounds__(256)
void build_C4(const float* __restrict__ Yr, float* __restrict__ C) {
    int idx = blockIdx.x * 256 + threadIdx.x;
    if (idx >= 100 * 800 * 200) return;
    int j4 = (idx % 200) * 4; int tt = idx / 200;
    int i = tt % 800;         int b = tt / 800;
    const float* y = Yr + b * 800;
    f32x4 v;
    #pragma unroll
    for (int r = 0; r < 4; r++) {
        int k = i - (j4 + r);
        k += (k >> 31) & 800;
        v[r] = y[k] * 0.035355339059327376f;
    }
    ((f32x4*)C)[idx] = v;
}

__global__ __launch_bounds__(256)
void convT5(const u16* __restrict__ in, const u16* __restrict__ w,
            const float* __restrict__ bias, float* __restrict__ out) {
    int idx = blockIdx.x * 256 + threadIdx.x;
    if (idx >= 100 * 49 * 49) return;
    int ox = idx % 49; int t2 = idx / 49;
    int oy = t2 % 49;  int b = t2 / 49;
    float acc = bias[0];
    for (int ky = 0; ky < 3; ky++) {
        int iy = oy - ky;
        if ((unsigned)iy >= 47u) continue;
        for (int kx = 0; kx < 3; kx++) {
            int ix = ox - kx;
            if ((unsigned)ix >= 47u) continue;
            const uint4* ip = (const uint4*)(in + (((size_t)b * 47 + iy) * 47 + ix) * 64);
            const uint4* wp = (const uint4*)(w + (ky * 3 + kx) * 64);
            #pragma unroll
            for (int g = 0; g < 8; g++) {
                uint4 av = ip[g], wv = wp[g];
                const unsigned* aa = (const unsigned*)&av;
                const unsigned* ww = (const unsigned*)&wv;
                #pragma unroll
                for (int h = 0; h < 4; h++) {
                    float a0 = __builtin_bit_cast(float, aa[h] << 16);
                    float a1 = __builtin_bit_cast(float, aa[h] & 0xFFFF0000u);
                    float w0 = __builtin_bit_cast(float, ww[h] << 16);
                    float w1 = __builtin_bit_cast(float, ww[h] & 0xFFFF0000u);
                    acc = fmaf(a0, w0, acc);
                    acc = fmaf(a1, w1, acc);
                }
            }
        }
    }
    out[idx] = acc;
}

// ===================== host helpers =====================
struct CTClass { int T, OHc, OWc, dyp, dxp, off, K; };
static void ct_params(int P, int OH, int OW, int CIN, int OC, CTClass cls[4]) {
    int off = 0;
    for (int c = 0; c < 4; c++) {
        int cy = c >> 1, cx = c & 1;
        int kys[2], dys[2], nky = 0, kxs[2], dxs[2], nkx = 0;
        for (int ky = 0; ky < 3; ky++)
            if (((cy + P + ky) & 1) == 0) { kys[nky] = ky; dys[nky] = (cy + P - ky) / 2; nky++; }
        for (int kx = 0; kx < 3; kx++)
            if (((cx + P + kx) & 1) == 0) { kxs[nkx] = kx; dxs[nkx] = (cx + P - kx) / 2; nkx++; }
        CTClass& cc = cls[c];
        cc.T = nky * nkx;
        cc.OHc = (OH - cy + 1) >> 1; cc.OWc = (OW - cx + 1) >> 1;
        cc.dyp = 0; cc.dxp = 0;
        int ti = 0;
        for (int a = 0; a < nky; a++)
            for (int b2 = 0; b2 < nkx; b2++, ti++) {
                cc.dyp |= (dys[a] & 255) << (8 * ti);
                cc.dxp |= (dxs[b2] & 255) << (8 * ti);
            }
        cc.off = off; cc.K = CIN * cc.T;
        off += OC * cc.K;
    }
}

template<int BM>
static void launch_ct(hipStream_t s, const u16* in, const u16* W, const float* bias, u16* outp,
                      int lgC, int OC, int IH, int IW, int OH, int OW, const CTClass* cls) {
    int maxMT = 0;
    for (int c = 0; c < 4; c++) {
        int mt = (100 * cls[c].OHc * cls[c].OWc + BM - 1) / BM;
        if (mt > maxMT) maxMT = mt;
    }
    dim3 g(maxMT, (OC + 63) / 64, 4);
    gemm_ct<BM><<<g, 256, 0, s>>>(in, W, bias, outp, OC, lgC, IH, IW, OH, OW,
        make_int4(cls[0].K, cls[1].K, cls[2].K, cls[3].K),
        make_int4(100*cls[0].OHc*cls[0].OWc, 100*cls[1].OHc*cls[1].OWc,
                  100*cls[2].OHc*cls[2].OWc, 100*cls[3].OHc*cls[3].OWc),
        make_int4(cls[0].OHc, cls[1].OHc, cls[2].OHc, cls[3].OHc),
        make_int4(cls[0].OWc, cls[1].OWc, cls[2].OWc, cls[3].OWc),
        make_int4(cls[0].off, cls[1].off, cls[2].off, cls[3].off),
        make_int4(cls[0].dyp, cls[1].dyp, cls[2].dyp, cls[3].dyp),
        make_int4(cls[0].dxp, cls[1].dxp, cls[2].dxp, cls[3].dxp));
}

extern "C" void kernel_launch(void* const* d_in, const int* in_sizes, int n_in,
                              void* d_out, int out_size, void* d_ws, size_t ws_size,
                              hipStream_t stream) {
    const float* x    = (const float*)d_in[0];
    const float* c1w  = (const float*)d_in[1];  const float* c1b = (const float*)d_in[2];
    const float* c2w  = (const float*)d_in[3];  const float* c2b = (const float*)d_in[4];
    const float* c3w  = (const float*)d_in[5];  const float* c3b = (const float*)d_in[6];
    const float* c4w  = (const float*)d_in[7];  const float* c4b = (const float*)d_in[8];
    const float* fcw  = (const float*)d_in[9];  const float* fcb = (const float*)d_in[10];
    const float* decw = (const float*)d_in[11]; const float* decb = (const float*)d_in[12];
    const float* t1w  = (const float*)d_in[13]; const float* t1b = (const float*)d_in[14];
    const float* t2w  = (const float*)d_in[15]; const float* t2b = (const float*)d_in[16];
    const float* t3w  = (const float*)d_in[17]; const float* t3b = (const float*)d_in[18];
    const float* t4w  = (const float*)d_in[19]; const float* t4b = (const float*)d_in[20];
    const float* t5w  = (const float*)d_in[21]; const float* t5b = (const float*)d_in[22];

    float* out = (float*)d_out;
    float* d_final = out;
    float* Cmat    = out + 240100;
    float* eig     = out + 240100 + 64000000;

    float* ws = (float*)d_ws;
    // ---- encoder-phase workspace (float units) ----
    u16*   h1    = (u16*)(ws);                 // 13,107,200 bf16
    u16*   W_fc  = (u16*)(ws);                 // reuse @0 after conv2
    u16*   h2    = (u16*)(ws + 6553600);
    u16*   h3    = (u16*)(ws + 9830400);
    u16*   W_c2  = (u16*)(ws + 13107200);
    u16*   W_c3  = (u16*)(ws + 13254656);
    u16*   W_c4  = (u16*)(ws + 14434304);
    float* h4f   = ws + 19152896;              // 1,638,400 f32
    u16*   h4    = (u16*)(ws + 20791296);
    float* accs  = ws + 21610496;              // 8,192 f32 (4 layer slices)
    float* facc  = ws + 21618688;              // 80,000 f32
    float* Yr    = ws + 21698688;              // 80,000 f32
    u16*   Yrb   = (u16*)(ws + 21778688);      // 80,000 bf16
    u16*   d0    = (u16*)(ws + 21818688);      // 921,600 bf16
    u16*   W_dec = (u16*)(ws + 22279488);      // 7,372,800 bf16 -> ends 25,965,888
    float* acc1 = accs, *acc2 = accs + 2048, *acc3 = accs + 4096, *acc4 = accs + 6144;
    // ---- decoder-phase (encoder region dead) ----
    u16*   W_t   = (u16*)(ws);                 // up to 4,718,592 bf16
    u16*   tmpw  = (u16*)(ws + 2359296);
    u16*   o1    = (u16*)(ws + 4718592);       // 1,280,000 bf16
    u16*   o2    = (u16*)(ws + 5358592);       // 3,097,600 bf16
    u16*   o3    = (u16*)(ws + 6907392);       // 6,771,200 bf16
    u16*   o4    = (u16*)(ws + 10292992);      // 14,137,600 bf16
    u16*   W_t5  = (u16*)(ws + 17361792);

    #define GRID(n) dim3(((n) + 255) / 256)

    // clear all BN-stat slices + facc in one fill
    hipMemsetAsync(accs, 0, (8192 + 80000) * 4, stream);

    // ======== encoder ========
    conv1_nhwc<<<GRID(13107200), 256, 0, stream>>>(x, c1w, c1b, h1);
    bnstat<u16><<<1024, 256, 0, stream>>>(h1, acc1, 128, 13107200);
    bnapply<u16><<<GRID(13107200), 256, 0, stream>>>(h1, h1, acc1, 128, 13107200, 1.f / 102400.f);

    convw_prep<<<GRID(294912), 256, 0, stream>>>(c2w, W_c2, 7, 294912);
    gemm<1, 0, 128, 128, 0, true><<<dim3(200, 2, 1), 256, 0, stream>>>(
        h1, W_c2, c2b, h2, acc2, 25600, 256, 1152, 7, 32, 32, 16, 16, 1152);
    bnapply<u16><<<GRID(6553600), 256, 0, stream>>>(h2, h2, acc2, 256, 6553600, 1.f / 25600.f);

    convw_prep<<<GRID(2359296), 256, 0, stream>>>(c3w, W_c3, 8, 2359296);
    gemm<1, 0, 128, 128, 1, true><<<dim3(400, 1, 1), 256, 0, stream>>>(
        h2, W_c3, c3b, h3, acc3, 6400, 1024, 2304, 8, 16, 16, 8, 8, 2304);
    bnapply<u16><<<GRID(6553600), 256, 0, stream>>>(h3, h3, acc3, 1024, 6553600, 1.f / 6400.f);

    convw_prep<<<GRID(9437184), 256, 0, stream>>>(c4w, W_c4, 10, 9437184);
    hipMemsetAsync(h4f, 0, 1638400 * 4, stream);
    gemm<1, 1, 64, 128, 1, false><<<dim3(400, 1, 1), 256, 0, stream>>>(
        h3, W_c4, c4b, h4f, nullptr, 1600, 1024, 9216, 10, 8, 8, 4, 4, 4608);
    bnstat<float><<<1024, 256, 0, stream>>>(h4f, acc4, 1024, 1638400);
    bnapply<float><<<GRID(1638400), 256, 0, stream>>>(h4f, h4, acc4, 1024, 1638400, 1.f / 1600.f);

    // ======== fc (split-K z=16) ========
    fcw_prep<<<dim3(25, 32, 16), 256, 0, stream>>>(fcw, W_fc);
    gemm<0, 4, 64, 64, 0, false><<<dim3(2, 13, 16), 256, 0, stream>>>(
        h4, W_fc, nullptr, facc, nullptr, 100, 800, 16384, 0, 0, 0, 0, 0, 1024);
    finalize_relu<<<GRID(80000), 256, 0, stream>>>(facc, fcb, eig);

    // ======== FFT block ========
    dft_real<<<dim3(100), 256, 0, stream>>>(eig, Yr, Yrb);
    build_C4<<<GRID(16000000), 256, 0, stream>>>(Yr, Cmat);

    // ======== dec matmul ========
    transpose_cvt<<<dim3(288, 25), 256, 0, stream>>>(decw, W_dec, 800, 9216);
    gemm<0, 5, 64, 64, 0, false><<<dim3(2, 144, 1), 256, 0, stream>>>(
        Yrb, W_dec, decb, d0, nullptr, 100, 9216, 800, 0, 0, 0, 0, 0, 800);

    // ======== decoder convT stack ========
    CTClass c1c[4], c2c[4], c3c[4], c4c[4];
    ct_params(1, 5, 5, 1024, 512, c1c);
    ct_params(0, 11, 11, 512, 256, c2c);
    ct_params(0, 23, 23, 256, 128, c3c);
    ct_params(0, 47, 47, 128, 64, c4c);

    transpose_cvt<<<dim3(144, 32), 256, 0, stream>>>(t1w, tmpw, 1024, 4608);
    ctw_gather<<<GRID(524288), 256, 0, stream>>>(tmpw, W_t, 1024, 10, 512, 1);
    launch_ct<64>(stream, d0, W_t, t1b, o1, 10, 512, 3, 3, 5, 5, c1c);

    transpose_cvt<<<dim3(72, 16), 256, 0, stream>>>(t2w, tmpw, 512, 2304);
    ctw_gather<<<GRID(131072), 256, 0, stream>>>(tmpw, W_t, 512, 9, 256, 0);
    launch_ct<64>(stream, o1, W_t, t2b, o2, 9, 256, 5, 5, 11, 11, c2c);

    transpose_cvt<<<dim3(36, 8), 256, 0, stream>>>(t3w, tmpw, 256, 1152);
    ctw_gather<<<GRID(32768), 256, 0, stream>>>(tmpw, W_t, 256, 8, 128, 0);
    launch_ct<64>(stream, o2, W_t, t3b, o3, 8, 128, 11, 11, 23, 23, c3c);

    transpose_cvt<<<dim3(18, 4), 256, 0, stream>>>(t4w, tmpw, 128, 576);
    ctw_gather<<<GRID(8192), 256, 0, stream>>>(tmpw, W_t, 128, 7, 64, 0);
    launch_ct<128>(stream, o3, W_t, t4b, o4, 7, 64, 23, 23, 47, 47, c4c);

    wt5_prep<<<GRID(576), 256, 0, stream>>>(t5w, W_t5);
    convT5<<<GRID(240100), 256, 0, stream>>>(o4, W_t5, t5b, d_final);

    #undef GRID
}